// Round 3
// baseline (510.695 us; speedup 1.0000x reference)
//
#include <hip/hip_runtime.h>
#include <hip/hip_bf16.h>

#define N_NODES 100000
#define N_EDGES 1600000
#define F_IN 128
#define HID 64
#define SCAN_NB 98  // ceil(100000/1024)

typedef __attribute__((ext_vector_type(8))) short short8;

__device__ __forceinline__ float bfbits2f(unsigned short u) {
    union { unsigned int i; float f; } v;
    v.i = ((unsigned int)u) << 16;
    return v.f;
}
__device__ __forceinline__ unsigned short f2bfbits(float f) {
    union { float f; unsigned int i; } v;
    v.f = f;
    unsigned int r = v.i + 0x7FFFu + ((v.i >> 16) & 1u);  // RNE
    return (unsigned short)(r >> 16);
}
__device__ __forceinline__ unsigned int pack2bf(float a, float b) {
    return ((unsigned int)f2bfbits(b) << 16) | (unsigned int)f2bfbits(a);
}
__device__ __forceinline__ float lo_bf(unsigned int w) { return bfbits2f((unsigned short)(w & 0xFFFF)); }
__device__ __forceinline__ float hi_bf(unsigned int w) { return bfbits2f((unsigned short)(w >> 16)); }

// ---- detect flags AND zero deg; block 0 does flag logic ----
__global__ void k_detect(const int* __restrict__ ei, const unsigned int* __restrict__ x32,
                         int* __restrict__ flag, int* __restrict__ deg) {
    int gid = blockIdx.x * 1024 + threadIdx.x;
    if (gid < N_NODES) deg[gid] = 0;
    if (blockIdx.x != 0) return;
    __shared__ int s_odd, s_cnt;
    if (threadIdx.x == 0) { s_odd = 0; s_cnt = 0; }
    __syncthreads();
    int t = threadIdx.x;  // 1024 threads
    if (ei[2 * t + 1] != 0) atomicOr(&s_odd, 1);
    if (t < 256) {
        unsigned int u = x32[t];
        unsigned int e = (u >> 7) & 0xFF;
        if (e >= 0x68 && e <= 0x97) atomicAdd(&s_cnt, 1);
    }
    __syncthreads();
    if (t == 0) {
        flag[0] = (s_odd == 0) ? 1 : 0;
        flag[1] = (s_cnt >= 160) ? 1 : 0;
    }
}

__device__ __forceinline__ int clampN(int v) {
    v = v < 0 ? 0 : v;
    return v > (N_NODES - 1) ? (N_NODES - 1) : v;
}
__device__ __forceinline__ int load_row(const int* __restrict__ ei, int f, int e) {
    return clampN(f ? ei[2 * e] : ei[e]);
}
__device__ __forceinline__ int load_col(const int* __restrict__ ei, int f, int e) {
    return clampN(f ? ei[2 * (N_EDGES + e)] : ei[N_EDGES + e]);
}

// ---- fp32 weight scratch layout (floats) ----
#define WF_W1   0
#define WF_W2   8192
#define WF_L1W  12288
#define WF_B1   20480
#define WF_B2   20544
#define WF_L1B  20608
#define WF_L2W  20672
#define WF_L2B  20800
#define WF_TOT  20802

__global__ void k_prep(const void* W1, const void* W2, const void* L1W,
                       const void* b1, const void* b2, const void* L1b,
                       const void* L2W, const void* L2b,
                       const int* __restrict__ flag, float* __restrict__ Wf) {
    int idx = blockIdx.x * blockDim.x + threadIdx.x;
    if (idx >= WF_TOT) return;
    int bf = flag[1];
    const void* src; int k;
    if      (idx < WF_W2)  { src = W1;  k = idx; }
    else if (idx < WF_L1W) { src = W2;  k = idx - WF_W2; }
    else if (idx < WF_B1)  { src = L1W; k = idx - WF_L1W; }
    else if (idx < WF_B2)  { src = b1;  k = idx - WF_B1; }
    else if (idx < WF_L1B) { src = b2;  k = idx - WF_B2; }
    else if (idx < WF_L2W) { src = L1b; k = idx - WF_L1B; }
    else if (idx < WF_L2B) { src = L2W; k = idx - WF_L2W; }
    else                   { src = L2b; k = idx - WF_L2B; }
    Wf[idx] = bf ? bfbits2f(((const unsigned short*)src)[k]) : ((const float*)src)[k];
}

// ---- deg count only (pos array eliminated; fill re-derives rank via cursor atomic) ----
__global__ void k_deg(const int* __restrict__ ei, const int* __restrict__ flag,
                      int* __restrict__ deg) {
    int e = blockIdx.x * blockDim.x + threadIdx.x;
    if (e >= N_EDGES) return;
    atomicAdd(&deg[load_col(ei, flag[0], e)], 1);
}

// ---- CSR build: scan1 also computes dinv and zeroes deg (cursor reuse) ----
__global__ void k_scan1(int* __restrict__ deg, int* __restrict__ rowptr,
                        int* __restrict__ bsum, float* __restrict__ dinv) {
    __shared__ int s[1024];
    int t = threadIdx.x, b = blockIdx.x;
    int i = b * 1024 + t;
    int v = (i < N_NODES) ? deg[i] : 0;
    if (i < N_NODES) {
        dinv[i] = rsqrtf((float)(v + 1));
        deg[i] = 0;  // becomes the fill cursor
    }
    s[t] = v; __syncthreads();
    for (int off = 1; off < 1024; off <<= 1) {
        int add = (t >= off) ? s[t - off] : 0;
        __syncthreads();
        s[t] += add;
        __syncthreads();
    }
    if (i < N_NODES) rowptr[i] = s[t] - v;
    if (t == 1023) bsum[b] = s[t];
}

__global__ void k_scan2(const int* __restrict__ bsum, int* __restrict__ boff,
                        int* __restrict__ rowptr) {
    __shared__ int s[128];
    int t = threadIdx.x;
    int v = (t < SCAN_NB) ? bsum[t] : 0;
    s[t] = v; __syncthreads();
    for (int off = 1; off < 128; off <<= 1) {
        int add = (t >= off) ? s[t - off] : 0;
        __syncthreads();
        s[t] += add;
        __syncthreads();
    }
    if (t < SCAN_NB) boff[t] = s[t] - v;
    if (t == 0) rowptr[N_NODES] = N_EDGES;
}

__global__ void k_scan3(int* __restrict__ rowptr, const int* __restrict__ boff) {
    int t = threadIdx.x, b = blockIdx.x;
    int i = b * 1024 + t;
    if (i < N_NODES) rowptr[i] += boff[b];
}

// ---- fill: ONE scattered 4-B store per edge; rank via cursor atomic (order within
// a column is irrelevant: aggregation is a sum) ----
__global__ void k_fill(const int* __restrict__ ei, const int* __restrict__ flag,
                       const int* __restrict__ rowptr, int* __restrict__ cursor,
                       int* __restrict__ csr_src) {
    int e = blockIdx.x * blockDim.x + threadIdx.x;
    if (e >= N_EDGES) return;
    int f = flag[0];
    int r = load_row(ei, f, e), c = load_col(ei, f, e);
    int pos = atomicAdd(&cursor[c], 1);
    csr_src[rowptr[c] + pos] = r;
}

// ===== node tables: packed bf16 rows, 32 u32 (=64 ch) per node =====
__device__ __forceinline__ void fma8_32(const float* xv, const float* __restrict__ W,
                                        int k0, int coloff, float* acc) {
#pragma unroll
    for (int t = 0; t < 8; t++) {
        const float* wr = W + (k0 + t) * 64 + coloff;
#pragma unroll
        for (int j = 0; j < 32; j++) acc[j] = fmaf(xv[t], wr[j], acc[j]);
    }
}

// ---- layer-1 GEMM (wave-split): x [N,128] @ Wf[128,64] -> hs bf16; scale=dinv ----
__global__ void __launch_bounds__(256) k_gemm_in_ws(const void* __restrict__ x,
                                                    const float* __restrict__ Wf,
                                                    const float* __restrict__ dinv,
                                                    unsigned int* __restrict__ hs,
                                                    const int* __restrict__ flag) {
    int wv = __builtin_amdgcn_readfirstlane(threadIdx.x >> 6);  // 0..3, scalar
    int wid = blockIdx.x * 4 + wv;
    int group = wid >> 1;
    int half = wid & 1;          // scalar: col-half
    int lane = threadIdx.x & 63;
    int node = group * 64 + lane;
    if (node >= N_NODES) return;
    int bf = flag[1];
    int coloff = half * 32;
    float acc[32];
#pragma unroll
    for (int j = 0; j < 32; j++) acc[j] = 0.f;
    if (bf) {
        const unsigned short* xp = (const unsigned short*)x + (size_t)node * F_IN;
#pragma unroll 2
        for (int k0 = 0; k0 < F_IN; k0 += 8) {
            short8 raw = *(const short8*)(xp + k0);
            float xv[8];
#pragma unroll
            for (int t = 0; t < 8; t++) xv[t] = bfbits2f((unsigned short)raw[t]);
            fma8_32(xv, Wf, k0, coloff, acc);
        }
    } else {
        const float* xp = (const float*)x + (size_t)node * F_IN;
#pragma unroll 2
        for (int k0 = 0; k0 < F_IN; k0 += 8) {
            float4 a = *(const float4*)(xp + k0);
            float4 b = *(const float4*)(xp + k0 + 4);
            float xv[8] = {a.x, a.y, a.z, a.w, b.x, b.y, b.z, b.w};
            fma8_32(xv, Wf, k0, coloff, acc);
        }
    }
    float s = dinv[node];
    unsigned int* op = hs + (size_t)node * 32 + half * 16;
#pragma unroll
    for (int j = 0; j < 32; j += 2) op[j >> 1] = pack2bf(acc[j] * s, acc[j + 1] * s);
}

// ---- layer-2 GEMM (wave-split): in bf16 [N,64] @ W[64][64] -> out bf16; scale=dinv ----
__global__ void __launch_bounds__(256) k_gemm64_ws(const unsigned int* __restrict__ in,
                                                   const float* __restrict__ W,
                                                   const float* __restrict__ dinv,
                                                   unsigned int* __restrict__ out) {
    int wv = __builtin_amdgcn_readfirstlane(threadIdx.x >> 6);
    int wid = blockIdx.x * 4 + wv;
    int group = wid >> 1;
    int half = wid & 1;
    int lane = threadIdx.x & 63;
    int node = group * 64 + lane;
    if (node >= N_NODES) return;
    int coloff = half * 32;
    float acc[32];
#pragma unroll
    for (int j = 0; j < 32; j++) acc[j] = 0.f;
    const unsigned short* hp = (const unsigned short*)(in + (size_t)node * 32);
#pragma unroll 2
    for (int k0 = 0; k0 < 64; k0 += 8) {
        short8 raw = *(const short8*)(hp + k0);
        float xv[8];
#pragma unroll
        for (int t = 0; t < 8; t++) xv[t] = bfbits2f((unsigned short)raw[t]);
        fma8_32(xv, W, k0, coloff, acc);
    }
    float s = dinv[node];
    unsigned int* op = out + (size_t)node * 32 + half * 16;
#pragma unroll
    for (int j = 0; j < 32; j += 2) op[j >> 1] = pack2bf(acc[j] * s, acc[j + 1] * s);
}

// ---- edge-MLP projections (wave-split, 4 tasks): block = 64 nodes x 4 waves ----
__global__ void __launch_bounds__(256) k_pair_ws(unsigned int* __restrict__ h,
                                                 const float* __restrict__ W,  // L1W [128][64]
                                                 unsigned int* __restrict__ P1) {
    int task = __builtin_amdgcn_readfirstlane(threadIdx.x >> 6);  // 0..3, scalar
    int lane = threadIdx.x & 63;
    int node = blockIdx.x * 64 + lane;
    bool valid = node < N_NODES;
    int coloff = (task & 1) * 32;
    const float* Wb = W + (task >> 1) * 64 * 64;  // k-row base: P1 rows 0.., P2 rows 64..
    float acc[32];
#pragma unroll
    for (int j = 0; j < 32; j++) acc[j] = 0.f;
    if (valid) {
        const unsigned short* hp = (const unsigned short*)(h + (size_t)node * 32);
#pragma unroll 2
        for (int k0 = 0; k0 < 64; k0 += 8) {
            short8 raw = *(const short8*)(hp + k0);
            float xv[8];
#pragma unroll
            for (int t = 0; t < 8; t++) xv[t] = bfbits2f((unsigned short)raw[t]);
            fma8_32(xv, Wb, k0, coloff, acc);
        }
    }
    __syncthreads();  // all reads of this block's 64 h-rows complete before P2 writes
    if (valid) {
        unsigned int* op = (task < 2 ? P1 : h) + (size_t)node * 32 + coloff / 2;
#pragma unroll
        for (int j = 0; j < 32; j += 2) op[j >> 1] = pack2bf(acc[j], acc[j + 1]);
    }
}

// ---- fused aggregate: wave = 2 nodes; 32 lanes/node; x4 unroll for gather ILP ----
__global__ void __launch_bounds__(256) k_agg(const unsigned int* __restrict__ hs,
                                             const int* __restrict__ rowptr,
                                             const int* __restrict__ csr_src,
                                             const float* __restrict__ dinv,
                                             const float* __restrict__ bias,
                                             unsigned int* __restrict__ h) {
    int waves_per_blk = blockDim.x >> 6;
    int wid = blockIdx.x * waves_per_blk + (threadIdx.x >> 6);
    int lane = threadIdx.x & 63;
    int half = lane >> 5;
    int w = lane & 31;
    int node = wid * 2 + half;
    if (node >= N_NODES) return;
    unsigned int sw = hs[(size_t)node * 32 + w];
    float a0 = lo_bf(sw), a1 = hi_bf(sw);
    int k = rowptr[node], k1 = rowptr[node + 1];
    for (; k + 3 < k1; k += 4) {
        int s0 = csr_src[k], s1 = csr_src[k + 1], s2 = csr_src[k + 2], s3 = csr_src[k + 3];
        unsigned int w0 = hs[(size_t)s0 * 32 + w];
        unsigned int w1 = hs[(size_t)s1 * 32 + w];
        unsigned int w2 = hs[(size_t)s2 * 32 + w];
        unsigned int w3 = hs[(size_t)s3 * 32 + w];
        a0 += (lo_bf(w0) + lo_bf(w1)) + (lo_bf(w2) + lo_bf(w3));
        a1 += (hi_bf(w0) + hi_bf(w1)) + (hi_bf(w2) + hi_bf(w3));
    }
    for (; k < k1; k++) {
        unsigned int w0 = hs[(size_t)csr_src[k] * 32 + w];
        a0 += lo_bf(w0);
        a1 += hi_bf(w0);
    }
    float di = dinv[node];
    float v0 = fmaxf(fmaf(a0, di, bias[2 * w]), 0.f);
    float v1 = fmaxf(fmaf(a1, di, bias[2 * w + 1]), 0.f);
    h[(size_t)node * 32 + w] = pack2bf(v0, v1);
}

// ---- edge MLP, lane-cooperative + 2-edge ILP: 8 lanes per edge-pair.
// Each lane issues 4 independent uint4 loads up front (P1[r0],P2[c0],P1[r1],P2[c1])
// -> 32 random 128-B lines in flight per wave (2x the 1-edge version), wave count
// halves, weights amortize over 2 edges. Lane 0 stores both adjacent outputs
// coalesced (16 B fp32 / 8 B bf16).
__global__ void __launch_bounds__(256) k_edge(const int* __restrict__ ei,
                       const unsigned int* __restrict__ P1, const unsigned int* __restrict__ P2,
                       const float* __restrict__ Wf, const int* __restrict__ flag,
                       void* __restrict__ out) {
    int tid = blockIdx.x * 256 + threadIdx.x;
    int g = tid >> 3;       // edge-pair index: edges 2g, 2g+1
    int k = tid & 7;        // sub-lane: channels j = 8k .. 8k+7
    int e0 = g * 2;
    if (e0 >= N_EDGES) return;  // N_EDGES even -> e0+1 always valid
    int f = flag[0];
    int r0 = load_row(ei, f, e0),     c0 = load_col(ei, f, e0);
    int r1 = load_row(ei, f, e0 + 1), c1 = load_col(ei, f, e0 + 1);
    // issue all 4 gathers before any compute
    uint4 ua0 = *(const uint4*)(P1 + (size_t)r0 * 32 + k * 4);
    uint4 ub0 = *(const uint4*)(P2 + (size_t)c0 * 32 + k * 4);
    uint4 ua1 = *(const uint4*)(P1 + (size_t)r1 * 32 + k * 4);
    uint4 ub1 = *(const uint4*)(P2 + (size_t)c1 * 32 + k * 4);
    float l1b[8], l2w[16];
#pragma unroll
    for (int t = 0; t < 8; t++) l1b[t] = Wf[WF_L1B + k * 8 + t];
#pragma unroll
    for (int t = 0; t < 16; t++) l2w[t] = Wf[WF_L2W + k * 16 + t];
    unsigned int wa0[4] = {ua0.x, ua0.y, ua0.z, ua0.w};
    unsigned int wb0[4] = {ub0.x, ub0.y, ub0.z, ub0.w};
    unsigned int wa1[4] = {ua1.x, ua1.y, ua1.z, ua1.w};
    unsigned int wb1[4] = {ub1.x, ub1.y, ub1.z, ub1.w};
    float s00 = 0.f, s01 = 0.f, s10 = 0.f, s11 = 0.f;
#pragma unroll
    for (int t = 0; t < 4; t++) {
        float z;
        z = fmaxf(lo_bf(wa0[t]) + lo_bf(wb0[t]) + l1b[2 * t], 0.f);
        s00 = fmaf(z, l2w[4 * t + 0], s00); s01 = fmaf(z, l2w[4 * t + 1], s01);
        z = fmaxf(hi_bf(wa0[t]) + hi_bf(wb0[t]) + l1b[2 * t + 1], 0.f);
        s00 = fmaf(z, l2w[4 * t + 2], s00); s01 = fmaf(z, l2w[4 * t + 3], s01);
        z = fmaxf(lo_bf(wa1[t]) + lo_bf(wb1[t]) + l1b[2 * t], 0.f);
        s10 = fmaf(z, l2w[4 * t + 0], s10); s11 = fmaf(z, l2w[4 * t + 1], s11);
        z = fmaxf(hi_bf(wa1[t]) + hi_bf(wb1[t]) + l1b[2 * t + 1], 0.f);
        s10 = fmaf(z, l2w[4 * t + 2], s10); s11 = fmaf(z, l2w[4 * t + 3], s11);
    }
#pragma unroll
    for (int off = 1; off < 8; off <<= 1) {
        s00 += __shfl_xor(s00, off);
        s01 += __shfl_xor(s01, off);
        s10 += __shfl_xor(s10, off);
        s11 += __shfl_xor(s11, off);
    }
    if (k == 0) {
        float b0f = Wf[WF_L2B + 0], b1f = Wf[WF_L2B + 1];
        float z00 = s00 + b0f, z01 = s01 + b1f;
        float z10 = s10 + b0f, z11 = s11 + b1f;
        float m0 = fmaxf(z00, z01);
        float lse0 = m0 + __logf(__expf(z00 - m0) + __expf(z01 - m0));
        float m1 = fmaxf(z10, z11);
        float lse1 = m1 + __logf(__expf(z10 - m1) + __expf(z11 - m1));
        if (flag[1]) {
            uint2 v; v.x = pack2bf(z00 - lse0, z01 - lse0); v.y = pack2bf(z10 - lse1, z11 - lse1);
            *(uint2*)((unsigned int*)out + e0) = v;
        } else {
            float4 v; v.x = z00 - lse0; v.y = z01 - lse0; v.z = z10 - lse1; v.w = z11 - lse1;
            *(float4*)((float2*)out + e0) = v;
        }
    }
}

extern "C" void kernel_launch(void* const* d_in, const int* in_sizes, int n_in,
                              void* d_out, int out_size, void* d_ws, size_t ws_size,
                              hipStream_t stream) {
    const void* x   = d_in[0];
    const int*  ei  = (const int*)d_in[1];

    char* ws = (char*)d_ws;
    constexpr size_t KB = 1024;

    int*   deg    = (int*)(ws);                    // 400 KB (reused as fill cursor)
    float* dinv   = (float*)(ws + 400 * KB);       // 400 KB
    int*   rowptr = (int*)(ws + 800 * KB);         // 400 KB + 4
    int*   flag   = (int*)(ws + 1204 * KB);        // 8 B
    int*   bsum   = (int*)(ws + 1208 * KB);        // 392 B
    int*   boff   = (int*)(ws + 1212 * KB);        // 392 B
    float* Wf     = (float*)(ws + 1216 * KB);      // 83.2 KB -> ends 1299.2 KB
    int*   csrsrc = (int*)(ws + 7700 * KB);        // 6400 KB -> ends 14100
    unsigned int* hs = (unsigned int*)(ws + 20500 * KB);  // 12800 KB (later P1)
    unsigned int* h  = (unsigned int*)(ws + 33300 * KB);  // 12800 KB (later P2)

    // detect + deg-zero fused
    k_detect<<<SCAN_NB, 1024, 0, stream>>>(ei, (const unsigned int*)x, flag, deg);
    k_prep<<<(WF_TOT + 255) / 256, 256, 0, stream>>>(d_in[2], d_in[4], d_in[6], d_in[3],
                                                     d_in[5], d_in[7], d_in[8], d_in[9],
                                                     flag, Wf);
    k_deg<<<(N_EDGES + 255) / 256, 256, 0, stream>>>(ei, flag, deg);

    // CSR build (scan1 also emits dinv and zeroes deg -> cursor)
    k_scan1<<<SCAN_NB, 1024, 0, stream>>>(deg, rowptr, bsum, dinv);
    k_scan2<<<1, 128, 0, stream>>>(bsum, boff, rowptr);
    k_scan3<<<SCAN_NB, 1024, 0, stream>>>(rowptr, boff);
    k_fill<<<(N_EDGES + 255) / 256, 256, 0, stream>>>(ei, flag, rowptr, deg, csrsrc);

    // wave-split grids: 2 waves/node-group(64) for gemms, 4 task-waves/64-node block for pair
    const int G = (N_NODES + 63) / 64;          // 1563 node groups
    const int gemm_blocks = (G * 2 + 3) / 4;    // 782

    // layer 1
    k_gemm_in_ws<<<gemm_blocks, 256, 0, stream>>>(x, Wf + WF_W1, dinv, hs, flag);
    k_agg<<<(N_NODES / 2 + 3) / 4, 256, 0, stream>>>(hs, rowptr, csrsrc, dinv, Wf + WF_B1, h);

    // layer 2
    k_gemm64_ws<<<gemm_blocks, 256, 0, stream>>>(h, Wf + WF_W2, dinv, hs);
    k_agg<<<(N_NODES / 2 + 3) / 4, 256, 0, stream>>>(hs, rowptr, csrsrc, dinv, Wf + WF_B2, h);

    // edge MLP: P1 -> hs, P2 in place on h (barrier-protected); original-order edge pass
    k_pair_ws<<<G, 256, 0, stream>>>(h, Wf + WF_L1W, hs);
    // 8 lanes per edge-pair -> 4 threads/edge -> 6.4M threads
    k_edge<<<(N_EDGES * 4 + 255) / 256, 256, 0, stream>>>(ei, hs, h, Wf, flag, d_out);
}

// Round 4
// 427.043 us; speedup vs baseline: 1.1959x; 1.1959x over previous
//
#include <hip/hip_runtime.h>
#include <hip/hip_bf16.h>

#define N_NODES 100000
#define N_EDGES 1600000
#define F_IN 128
#define HID 64
#define SCAN_NB 98  // ceil(100000/1024)

typedef __attribute__((ext_vector_type(8))) short short8;

__device__ __forceinline__ float bfbits2f(unsigned short u) {
    union { unsigned int i; float f; } v;
    v.i = ((unsigned int)u) << 16;
    return v.f;
}
__device__ __forceinline__ unsigned short f2bfbits(float f) {
    union { float f; unsigned int i; } v;
    v.f = f;
    unsigned int r = v.i + 0x7FFFu + ((v.i >> 16) & 1u);  // RNE
    return (unsigned short)(r >> 16);
}
__device__ __forceinline__ unsigned int pack2bf(float a, float b) {
    return ((unsigned int)f2bfbits(b) << 16) | (unsigned int)f2bfbits(a);
}
__device__ __forceinline__ float lo_bf(unsigned int w) { return bfbits2f((unsigned short)(w & 0xFFFF)); }
__device__ __forceinline__ float hi_bf(unsigned int w) { return bfbits2f((unsigned short)(w >> 16)); }

// ---- detect flags AND zero deg; block 0 does flag logic ----
__global__ void k_detect(const int* __restrict__ ei, const unsigned int* __restrict__ x32,
                         int* __restrict__ flag, int* __restrict__ deg) {
    int gid = blockIdx.x * 1024 + threadIdx.x;
    if (gid < N_NODES) deg[gid] = 0;
    if (blockIdx.x != 0) return;
    __shared__ int s_odd, s_cnt;
    if (threadIdx.x == 0) { s_odd = 0; s_cnt = 0; }
    __syncthreads();
    int t = threadIdx.x;  // 1024 threads
    if (ei[2 * t + 1] != 0) atomicOr(&s_odd, 1);
    if (t < 256) {
        unsigned int u = x32[t];
        unsigned int e = (u >> 7) & 0xFF;
        if (e >= 0x68 && e <= 0x97) atomicAdd(&s_cnt, 1);
    }
    __syncthreads();
    if (t == 0) {
        flag[0] = (s_odd == 0) ? 1 : 0;
        flag[1] = (s_cnt >= 160) ? 1 : 0;
    }
}

__device__ __forceinline__ int clampN(int v) {
    v = v < 0 ? 0 : v;
    return v > (N_NODES - 1) ? (N_NODES - 1) : v;
}
__device__ __forceinline__ int load_row(const int* __restrict__ ei, int f, int e) {
    return clampN(f ? ei[2 * e] : ei[e]);
}
__device__ __forceinline__ int load_col(const int* __restrict__ ei, int f, int e) {
    return clampN(f ? ei[2 * (N_EDGES + e)] : ei[N_EDGES + e]);
}

// ---- fp32 weight scratch layout (floats) ----
#define WF_W1   0
#define WF_W2   8192
#define WF_L1W  12288
#define WF_B1   20480
#define WF_B2   20544
#define WF_L1B  20608
#define WF_L2W  20672
#define WF_L2B  20800
#define WF_TOT  20802

__global__ void k_prep(const void* W1, const void* W2, const void* L1W,
                       const void* b1, const void* b2, const void* L1b,
                       const void* L2W, const void* L2b,
                       const int* __restrict__ flag, float* __restrict__ Wf) {
    int idx = blockIdx.x * blockDim.x + threadIdx.x;
    if (idx >= WF_TOT) return;
    int bf = flag[1];
    const void* src; int k;
    if      (idx < WF_W2)  { src = W1;  k = idx; }
    else if (idx < WF_L1W) { src = W2;  k = idx - WF_W2; }
    else if (idx < WF_B1)  { src = L1W; k = idx - WF_L1W; }
    else if (idx < WF_B2)  { src = b1;  k = idx - WF_B1; }
    else if (idx < WF_L1B) { src = b2;  k = idx - WF_B2; }
    else if (idx < WF_L2W) { src = L1b; k = idx - WF_L1B; }
    else if (idx < WF_L2B) { src = L2W; k = idx - WF_L2W; }
    else                   { src = L2b; k = idx - WF_L2B; }
    Wf[idx] = bf ? bfbits2f(((const unsigned short*)src)[k]) : ((const float*)src)[k];
}

// ---- deg count + slot assignment: pos[e] = rank of edge e among edges with same col.
// The atomic's result has no in-kernel consumer chain (coalesced pos write), keeping
// the L2 atomic round-trip off the critical path; k_fill is then atomic-free.
__global__ void k_deg(const int* __restrict__ ei, const int* __restrict__ flag,
                      int* __restrict__ deg, int* __restrict__ pos) {
    int e = blockIdx.x * blockDim.x + threadIdx.x;
    if (e >= N_EDGES) return;
    pos[e] = atomicAdd(&deg[load_col(ei, flag[0], e)], 1);
}

// ---- CSR build: scan1 also computes dinv ----
__global__ void k_scan1(const int* __restrict__ deg, int* __restrict__ rowptr,
                        int* __restrict__ bsum, float* __restrict__ dinv) {
    __shared__ int s[1024];
    int t = threadIdx.x, b = blockIdx.x;
    int i = b * 1024 + t;
    int v = (i < N_NODES) ? deg[i] : 0;
    if (i < N_NODES) dinv[i] = rsqrtf((float)(v + 1));
    s[t] = v; __syncthreads();
    for (int off = 1; off < 1024; off <<= 1) {
        int add = (t >= off) ? s[t - off] : 0;
        __syncthreads();
        s[t] += add;
        __syncthreads();
    }
    if (i < N_NODES) rowptr[i] = s[t] - v;
    if (t == 1023) bsum[b] = s[t];
}

__global__ void k_scan2(const int* __restrict__ bsum, int* __restrict__ boff,
                        int* __restrict__ rowptr) {
    __shared__ int s[128];
    int t = threadIdx.x;
    int v = (t < SCAN_NB) ? bsum[t] : 0;
    s[t] = v; __syncthreads();
    for (int off = 1; off < 128; off <<= 1) {
        int add = (t >= off) ? s[t - off] : 0;
        __syncthreads();
        s[t] += add;
        __syncthreads();
    }
    if (t < SCAN_NB) boff[t] = s[t] - v;
    if (t == 0) rowptr[N_NODES] = N_EDGES;
}

__global__ void k_scan3(int* __restrict__ rowptr, const int* __restrict__ boff) {
    int t = threadIdx.x, b = blockIdx.x;
    int i = b * 1024 + t;
    if (i < N_NODES) rowptr[i] += boff[b];
}

// ---- fill: ONE scattered 4-B store per edge, no atomic (pos precomputed in k_deg) ----
__global__ void k_fill(const int* __restrict__ ei, const int* __restrict__ flag,
                       const int* __restrict__ rowptr, const int* __restrict__ pos,
                       int* __restrict__ csr_src) {
    int e = blockIdx.x * blockDim.x + threadIdx.x;
    if (e >= N_EDGES) return;
    int f = flag[0];
    int r = load_row(ei, f, e), c = load_col(ei, f, e);
    csr_src[rowptr[c] + pos[e]] = r;
}

// ===== node tables: packed bf16 rows, 32 u32 (=64 ch) per node =====
__device__ __forceinline__ void fma8_32(const float* xv, const float* __restrict__ W,
                                        int k0, int coloff, float* acc) {
#pragma unroll
    for (int t = 0; t < 8; t++) {
        const float* wr = W + (k0 + t) * 64 + coloff;
#pragma unroll
        for (int j = 0; j < 32; j++) acc[j] = fmaf(xv[t], wr[j], acc[j]);
    }
}

// ---- layer-1 GEMM (wave-split): x [N,128] @ Wf[128,64] -> hs bf16; scale=dinv ----
__global__ void __launch_bounds__(256) k_gemm_in_ws(const void* __restrict__ x,
                                                    const float* __restrict__ Wf,
                                                    const float* __restrict__ dinv,
                                                    unsigned int* __restrict__ hs,
                                                    const int* __restrict__ flag) {
    int wv = __builtin_amdgcn_readfirstlane(threadIdx.x >> 6);  // 0..3, scalar
    int wid = blockIdx.x * 4 + wv;
    int group = wid >> 1;
    int half = wid & 1;          // scalar: col-half
    int lane = threadIdx.x & 63;
    int node = group * 64 + lane;
    if (node >= N_NODES) return;
    int bf = flag[1];
    int coloff = half * 32;
    float acc[32];
#pragma unroll
    for (int j = 0; j < 32; j++) acc[j] = 0.f;
    if (bf) {
        const unsigned short* xp = (const unsigned short*)x + (size_t)node * F_IN;
#pragma unroll 2
        for (int k0 = 0; k0 < F_IN; k0 += 8) {
            short8 raw = *(const short8*)(xp + k0);
            float xv[8];
#pragma unroll
            for (int t = 0; t < 8; t++) xv[t] = bfbits2f((unsigned short)raw[t]);
            fma8_32(xv, Wf, k0, coloff, acc);
        }
    } else {
        const float* xp = (const float*)x + (size_t)node * F_IN;
#pragma unroll 2
        for (int k0 = 0; k0 < F_IN; k0 += 8) {
            float4 a = *(const float4*)(xp + k0);
            float4 b = *(const float4*)(xp + k0 + 4);
            float xv[8] = {a.x, a.y, a.z, a.w, b.x, b.y, b.z, b.w};
            fma8_32(xv, Wf, k0, coloff, acc);
        }
    }
    float s = dinv[node];
    unsigned int* op = hs + (size_t)node * 32 + half * 16;
#pragma unroll
    for (int j = 0; j < 32; j += 2) op[j >> 1] = pack2bf(acc[j] * s, acc[j + 1] * s);
}

// ---- layer-2 GEMM (wave-split): in bf16 [N,64] @ W[64][64] -> out bf16; scale=dinv ----
__global__ void __launch_bounds__(256) k_gemm64_ws(const unsigned int* __restrict__ in,
                                                   const float* __restrict__ W,
                                                   const float* __restrict__ dinv,
                                                   unsigned int* __restrict__ out) {
    int wv = __builtin_amdgcn_readfirstlane(threadIdx.x >> 6);
    int wid = blockIdx.x * 4 + wv;
    int group = wid >> 1;
    int half = wid & 1;
    int lane = threadIdx.x & 63;
    int node = group * 64 + lane;
    if (node >= N_NODES) return;
    int coloff = half * 32;
    float acc[32];
#pragma unroll
    for (int j = 0; j < 32; j++) acc[j] = 0.f;
    const unsigned short* hp = (const unsigned short*)(in + (size_t)node * 32);
#pragma unroll 2
    for (int k0 = 0; k0 < 64; k0 += 8) {
        short8 raw = *(const short8*)(hp + k0);
        float xv[8];
#pragma unroll
        for (int t = 0; t < 8; t++) xv[t] = bfbits2f((unsigned short)raw[t]);
        fma8_32(xv, W, k0, coloff, acc);
    }
    float s = dinv[node];
    unsigned int* op = out + (size_t)node * 32 + half * 16;
#pragma unroll
    for (int j = 0; j < 32; j += 2) op[j >> 1] = pack2bf(acc[j] * s, acc[j + 1] * s);
}

// ---- edge-MLP projections (wave-split, 4 tasks): block = 64 nodes x 4 waves ----
__global__ void __launch_bounds__(256) k_pair_ws(unsigned int* __restrict__ h,
                                                 const float* __restrict__ W,  // L1W [128][64]
                                                 unsigned int* __restrict__ P1) {
    int task = __builtin_amdgcn_readfirstlane(threadIdx.x >> 6);  // 0..3, scalar
    int lane = threadIdx.x & 63;
    int node = blockIdx.x * 64 + lane;
    bool valid = node < N_NODES;
    int coloff = (task & 1) * 32;
    const float* Wb = W + (task >> 1) * 64 * 64;  // k-row base: P1 rows 0.., P2 rows 64..
    float acc[32];
#pragma unroll
    for (int j = 0; j < 32; j++) acc[j] = 0.f;
    if (valid) {
        const unsigned short* hp = (const unsigned short*)(h + (size_t)node * 32);
#pragma unroll 2
        for (int k0 = 0; k0 < 64; k0 += 8) {
            short8 raw = *(const short8*)(hp + k0);
            float xv[8];
#pragma unroll
            for (int t = 0; t < 8; t++) xv[t] = bfbits2f((unsigned short)raw[t]);
            fma8_32(xv, Wb, k0, coloff, acc);
        }
    }
    __syncthreads();  // all reads of this block's 64 h-rows complete before P2 writes
    if (valid) {
        unsigned int* op = (task < 2 ? P1 : h) + (size_t)node * 32 + coloff / 2;
#pragma unroll
        for (int j = 0; j < 32; j += 2) op[j >> 1] = pack2bf(acc[j], acc[j + 1]);
    }
}

// ---- fused aggregate: wave = 2 nodes; 32 lanes/node; x4 unroll for gather ILP ----
__global__ void __launch_bounds__(256) k_agg(const unsigned int* __restrict__ hs,
                                             const int* __restrict__ rowptr,
                                             const int* __restrict__ csr_src,
                                             const float* __restrict__ dinv,
                                             const float* __restrict__ bias,
                                             unsigned int* __restrict__ h) {
    int waves_per_blk = blockDim.x >> 6;
    int wid = blockIdx.x * waves_per_blk + (threadIdx.x >> 6);
    int lane = threadIdx.x & 63;
    int half = lane >> 5;
    int w = lane & 31;
    int node = wid * 2 + half;
    if (node >= N_NODES) return;
    unsigned int sw = hs[(size_t)node * 32 + w];
    float a0 = lo_bf(sw), a1 = hi_bf(sw);
    int k = rowptr[node], k1 = rowptr[node + 1];
    for (; k + 3 < k1; k += 4) {
        int s0 = csr_src[k], s1 = csr_src[k + 1], s2 = csr_src[k + 2], s3 = csr_src[k + 3];
        unsigned int w0 = hs[(size_t)s0 * 32 + w];
        unsigned int w1 = hs[(size_t)s1 * 32 + w];
        unsigned int w2 = hs[(size_t)s2 * 32 + w];
        unsigned int w3 = hs[(size_t)s3 * 32 + w];
        a0 += (lo_bf(w0) + lo_bf(w1)) + (lo_bf(w2) + lo_bf(w3));
        a1 += (hi_bf(w0) + hi_bf(w1)) + (hi_bf(w2) + hi_bf(w3));
    }
    for (; k < k1; k++) {
        unsigned int w0 = hs[(size_t)csr_src[k] * 32 + w];
        a0 += lo_bf(w0);
        a1 += hi_bf(w0);
    }
    float di = dinv[node];
    float v0 = fmaxf(fmaf(a0, di, bias[2 * w]), 0.f);
    float v1 = fmaxf(fmaf(a1, di, bias[2 * w + 1]), 0.f);
    h[(size_t)node * 32 + w] = pack2bf(v0, v1);
}

// ---- edge MLP, lane-cooperative + 2-edge ILP: 8 lanes per edge-pair.
// Each lane issues 4 independent uint4 loads up front (P1[r0],P2[c0],P1[r1],P2[c1])
// -> 32 random 128-B lines in flight per wave, weights amortize over 2 edges.
// Lane 0 stores both adjacent outputs coalesced (16 B fp32 / 8 B bf16).
__global__ void __launch_bounds__(256) k_edge(const int* __restrict__ ei,
                       const unsigned int* __restrict__ P1, const unsigned int* __restrict__ P2,
                       const float* __restrict__ Wf, const int* __restrict__ flag,
                       void* __restrict__ out) {
    int tid = blockIdx.x * 256 + threadIdx.x;
    int g = tid >> 3;       // edge-pair index: edges 2g, 2g+1
    int k = tid & 7;        // sub-lane: channels j = 8k .. 8k+7
    int e0 = g * 2;
    if (e0 >= N_EDGES) return;  // N_EDGES even -> e0+1 always valid
    int f = flag[0];
    int r0 = load_row(ei, f, e0),     c0 = load_col(ei, f, e0);
    int r1 = load_row(ei, f, e0 + 1), c1 = load_col(ei, f, e0 + 1);
    // issue all 4 gathers before any compute
    uint4 ua0 = *(const uint4*)(P1 + (size_t)r0 * 32 + k * 4);
    uint4 ub0 = *(const uint4*)(P2 + (size_t)c0 * 32 + k * 4);
    uint4 ua1 = *(const uint4*)(P1 + (size_t)r1 * 32 + k * 4);
    uint4 ub1 = *(const uint4*)(P2 + (size_t)c1 * 32 + k * 4);
    float l1b[8], l2w[16];
#pragma unroll
    for (int t = 0; t < 8; t++) l1b[t] = Wf[WF_L1B + k * 8 + t];
#pragma unroll
    for (int t = 0; t < 16; t++) l2w[t] = Wf[WF_L2W + k * 16 + t];
    unsigned int wa0[4] = {ua0.x, ua0.y, ua0.z, ua0.w};
    unsigned int wb0[4] = {ub0.x, ub0.y, ub0.z, ub0.w};
    unsigned int wa1[4] = {ua1.x, ua1.y, ua1.z, ua1.w};
    unsigned int wb1[4] = {ub1.x, ub1.y, ub1.z, ub1.w};
    float s00 = 0.f, s01 = 0.f, s10 = 0.f, s11 = 0.f;
#pragma unroll
    for (int t = 0; t < 4; t++) {
        float z;
        z = fmaxf(lo_bf(wa0[t]) + lo_bf(wb0[t]) + l1b[2 * t], 0.f);
        s00 = fmaf(z, l2w[4 * t + 0], s00); s01 = fmaf(z, l2w[4 * t + 1], s01);
        z = fmaxf(hi_bf(wa0[t]) + hi_bf(wb0[t]) + l1b[2 * t + 1], 0.f);
        s00 = fmaf(z, l2w[4 * t + 2], s00); s01 = fmaf(z, l2w[4 * t + 3], s01);
        z = fmaxf(lo_bf(wa1[t]) + lo_bf(wb1[t]) + l1b[2 * t], 0.f);
        s10 = fmaf(z, l2w[4 * t + 0], s10); s11 = fmaf(z, l2w[4 * t + 1], s11);
        z = fmaxf(hi_bf(wa1[t]) + hi_bf(wb1[t]) + l1b[2 * t + 1], 0.f);
        s10 = fmaf(z, l2w[4 * t + 2], s10); s11 = fmaf(z, l2w[4 * t + 3], s11);
    }
#pragma unroll
    for (int off = 1; off < 8; off <<= 1) {
        s00 += __shfl_xor(s00, off);
        s01 += __shfl_xor(s01, off);
        s10 += __shfl_xor(s10, off);
        s11 += __shfl_xor(s11, off);
    }
    if (k == 0) {
        float b0f = Wf[WF_L2B + 0], b1f = Wf[WF_L2B + 1];
        float z00 = s00 + b0f, z01 = s01 + b1f;
        float z10 = s10 + b0f, z11 = s11 + b1f;
        float m0 = fmaxf(z00, z01);
        float lse0 = m0 + __logf(__expf(z00 - m0) + __expf(z01 - m0));
        float m1 = fmaxf(z10, z11);
        float lse1 = m1 + __logf(__expf(z10 - m1) + __expf(z11 - m1));
        if (flag[1]) {
            uint2 v; v.x = pack2bf(z00 - lse0, z01 - lse0); v.y = pack2bf(z10 - lse1, z11 - lse1);
            *(uint2*)((unsigned int*)out + e0) = v;
        } else {
            float4 v; v.x = z00 - lse0; v.y = z01 - lse0; v.z = z10 - lse1; v.w = z11 - lse1;
            *(float4*)((float2*)out + e0) = v;
        }
    }
}

extern "C" void kernel_launch(void* const* d_in, const int* in_sizes, int n_in,
                              void* d_out, int out_size, void* d_ws, size_t ws_size,
                              hipStream_t stream) {
    const void* x   = d_in[0];
    const int*  ei  = (const int*)d_in[1];

    char* ws = (char*)d_ws;
    constexpr size_t KB = 1024;

    int*   deg    = (int*)(ws);                    // 400 KB
    float* dinv   = (float*)(ws + 400 * KB);       // 400 KB
    int*   rowptr = (int*)(ws + 800 * KB);         // 400 KB + 4
    int*   flag   = (int*)(ws + 1204 * KB);        // 8 B
    int*   bsum   = (int*)(ws + 1208 * KB);        // 392 B
    int*   boff   = (int*)(ws + 1212 * KB);        // 392 B
    float* Wf     = (float*)(ws + 1216 * KB);      // 83.2 KB -> ends 1299.2 KB
    int*   pos    = (int*)(ws + 1300 * KB);        // 6400 KB -> ends 7700
    int*   csrsrc = (int*)(ws + 7700 * KB);        // 6400 KB -> ends 14100
    unsigned int* hs = (unsigned int*)(ws + 20500 * KB);  // 12800 KB (later P1)
    unsigned int* h  = (unsigned int*)(ws + 33300 * KB);  // 12800 KB (later P2)

    // detect + deg-zero fused
    k_detect<<<SCAN_NB, 1024, 0, stream>>>(ei, (const unsigned int*)x, flag, deg);
    k_prep<<<(WF_TOT + 255) / 256, 256, 0, stream>>>(d_in[2], d_in[4], d_in[6], d_in[3],
                                                     d_in[5], d_in[7], d_in[8], d_in[9],
                                                     flag, Wf);
    // deg count + per-edge slot rank (atomic return) -> fill needs no atomics
    k_deg<<<(N_EDGES + 255) / 256, 256, 0, stream>>>(ei, flag, deg, pos);

    // CSR build (scan1 also emits dinv)
    k_scan1<<<SCAN_NB, 1024, 0, stream>>>(deg, rowptr, bsum, dinv);
    k_scan2<<<1, 128, 0, stream>>>(bsum, boff, rowptr);
    k_scan3<<<SCAN_NB, 1024, 0, stream>>>(rowptr, boff);
    k_fill<<<(N_EDGES + 255) / 256, 256, 0, stream>>>(ei, flag, rowptr, pos, csrsrc);

    // wave-split grids: 2 waves/node-group(64) for gemms, 4 task-waves/64-node block for pair
    const int G = (N_NODES + 63) / 64;          // 1563 node groups
    const int gemm_blocks = (G * 2 + 3) / 4;    // 782

    // layer 1
    k_gemm_in_ws<<<gemm_blocks, 256, 0, stream>>>(x, Wf + WF_W1, dinv, hs, flag);
    k_agg<<<(N_NODES / 2 + 3) / 4, 256, 0, stream>>>(hs, rowptr, csrsrc, dinv, Wf + WF_B1, h);

    // layer 2
    k_gemm64_ws<<<gemm_blocks, 256, 0, stream>>>(h, Wf + WF_W2, dinv, hs);
    k_agg<<<(N_NODES / 2 + 3) / 4, 256, 0, stream>>>(hs, rowptr, csrsrc, dinv, Wf + WF_B2, h);

    // edge MLP: P1 -> hs, P2 in place on h (barrier-protected); original-order edge pass
    k_pair_ws<<<G, 256, 0, stream>>>(h, Wf + WF_L1W, hs);
    // 8 lanes per edge-pair -> 4 threads/edge -> 6.4M threads
    k_edge<<<(N_EDGES * 4 + 255) / 256, 256, 0, stream>>>(ei, hs, h, Wf, flag, d_out);
}

// Round 5
// 415.922 us; speedup vs baseline: 1.2279x; 1.0267x over previous
//
#include <hip/hip_runtime.h>
#include <hip/hip_bf16.h>

#define N_NODES 100000
#define N_EDGES 1600000
#define F_IN 128
#define HID 64
#define SCAN_NB 98  // ceil(100000/1024)

typedef __attribute__((ext_vector_type(8))) short short8;

__device__ __forceinline__ float bfbits2f(unsigned short u) {
    union { unsigned int i; float f; } v;
    v.i = ((unsigned int)u) << 16;
    return v.f;
}
__device__ __forceinline__ unsigned short f2bfbits(float f) {
    union { float f; unsigned int i; } v;
    v.f = f;
    unsigned int r = v.i + 0x7FFFu + ((v.i >> 16) & 1u);  // RNE
    return (unsigned short)(r >> 16);
}
__device__ __forceinline__ unsigned int pack2bf(float a, float b) {
    return ((unsigned int)f2bfbits(b) << 16) | (unsigned int)f2bfbits(a);
}
__device__ __forceinline__ float lo_bf(unsigned int w) { return bfbits2f((unsigned short)(w & 0xFFFF)); }
__device__ __forceinline__ float hi_bf(unsigned int w) { return bfbits2f((unsigned short)(w >> 16)); }

// ---- detect flags AND zero deg; block 0 does flag logic ----
__global__ void k_detect(const int* __restrict__ ei, const unsigned int* __restrict__ x32,
                         int* __restrict__ flag, int* __restrict__ deg) {
    int gid = blockIdx.x * 1024 + threadIdx.x;
    if (gid < N_NODES) deg[gid] = 0;
    if (blockIdx.x != 0) return;
    __shared__ int s_odd, s_cnt;
    if (threadIdx.x == 0) { s_odd = 0; s_cnt = 0; }
    __syncthreads();
    int t = threadIdx.x;  // 1024 threads
    if (ei[2 * t + 1] != 0) atomicOr(&s_odd, 1);
    if (t < 256) {
        unsigned int u = x32[t];
        unsigned int e = (u >> 7) & 0xFF;
        if (e >= 0x68 && e <= 0x97) atomicAdd(&s_cnt, 1);
    }
    __syncthreads();
    if (t == 0) {
        flag[0] = (s_odd == 0) ? 1 : 0;
        flag[1] = (s_cnt >= 160) ? 1 : 0;
    }
}

__device__ __forceinline__ int clampN(int v) {
    v = v < 0 ? 0 : v;
    return v > (N_NODES - 1) ? (N_NODES - 1) : v;
}
__device__ __forceinline__ int load_row(const int* __restrict__ ei, int f, int e) {
    return clampN(f ? ei[2 * e] : ei[e]);
}
__device__ __forceinline__ int load_col(const int* __restrict__ ei, int f, int e) {
    return clampN(f ? ei[2 * (N_EDGES + e)] : ei[N_EDGES + e]);
}

// ---- fp32 weight scratch layout (floats) ----
#define WF_W1   0
#define WF_W2   8192
#define WF_L1W  12288
#define WF_B1   20480
#define WF_B2   20544
#define WF_L1B  20608
#define WF_L2W  20672
#define WF_L2B  20800
#define WF_TOT  20802

__global__ void k_prep(const void* W1, const void* W2, const void* L1W,
                       const void* b1, const void* b2, const void* L1b,
                       const void* L2W, const void* L2b,
                       const int* __restrict__ flag, float* __restrict__ Wf) {
    int idx = blockIdx.x * blockDim.x + threadIdx.x;
    if (idx >= WF_TOT) return;
    int bf = flag[1];
    const void* src; int k;
    if      (idx < WF_W2)  { src = W1;  k = idx; }
    else if (idx < WF_L1W) { src = W2;  k = idx - WF_W2; }
    else if (idx < WF_B1)  { src = L1W; k = idx - WF_L1W; }
    else if (idx < WF_B2)  { src = b1;  k = idx - WF_B1; }
    else if (idx < WF_L1B) { src = b2;  k = idx - WF_B2; }
    else if (idx < WF_L2W) { src = L1b; k = idx - WF_L1B; }
    else if (idx < WF_L2B) { src = L2W; k = idx - WF_L2W; }
    else                   { src = L2b; k = idx - WF_L2B; }
    Wf[idx] = bf ? bfbits2f(((const unsigned short*)src)[k]) : ((const float*)src)[k];
}

// ---- deg count + slot assignment: pos[e] = rank of edge e among edges with same col.
// The atomic's result has no in-kernel consumer chain (coalesced pos write), keeping
// the L2 atomic round-trip off the critical path; k_fill is then atomic-free.
__global__ void k_deg(const int* __restrict__ ei, const int* __restrict__ flag,
                      int* __restrict__ deg, int* __restrict__ pos) {
    int e = blockIdx.x * blockDim.x + threadIdx.x;
    if (e >= N_EDGES) return;
    pos[e] = atomicAdd(&deg[load_col(ei, flag[0], e)], 1);
}

// ---- CSR build: scan1 also computes dinv ----
__global__ void k_scan1(const int* __restrict__ deg, int* __restrict__ rowptr,
                        int* __restrict__ bsum, float* __restrict__ dinv) {
    __shared__ int s[1024];
    int t = threadIdx.x, b = blockIdx.x;
    int i = b * 1024 + t;
    int v = (i < N_NODES) ? deg[i] : 0;
    if (i < N_NODES) dinv[i] = rsqrtf((float)(v + 1));
    s[t] = v; __syncthreads();
    for (int off = 1; off < 1024; off <<= 1) {
        int add = (t >= off) ? s[t - off] : 0;
        __syncthreads();
        s[t] += add;
        __syncthreads();
    }
    if (i < N_NODES) rowptr[i] = s[t] - v;
    if (t == 1023) bsum[b] = s[t];
}

__global__ void k_scan2(const int* __restrict__ bsum, int* __restrict__ boff,
                        int* __restrict__ rowptr) {
    __shared__ int s[128];
    int t = threadIdx.x;
    int v = (t < SCAN_NB) ? bsum[t] : 0;
    s[t] = v; __syncthreads();
    for (int off = 1; off < 128; off <<= 1) {
        int add = (t >= off) ? s[t - off] : 0;
        __syncthreads();
        s[t] += add;
        __syncthreads();
    }
    if (t < SCAN_NB) boff[t] = s[t] - v;
    if (t == 0) rowptr[N_NODES] = N_EDGES;
}

__global__ void k_scan3(int* __restrict__ rowptr, const int* __restrict__ boff) {
    int t = threadIdx.x, b = blockIdx.x;
    int i = b * 1024 + t;
    if (i < N_NODES) rowptr[i] += boff[b];
}

// ---- fill: ONE scattered 4-B store per edge, no atomic (pos precomputed in k_deg) ----
__global__ void k_fill(const int* __restrict__ ei, const int* __restrict__ flag,
                       const int* __restrict__ rowptr, const int* __restrict__ pos,
                       int* __restrict__ csr_src) {
    int e = blockIdx.x * blockDim.x + threadIdx.x;
    if (e >= N_EDGES) return;
    int f = flag[0];
    int r = load_row(ei, f, e), c = load_col(ei, f, e);
    csr_src[rowptr[c] + pos[e]] = r;
}

// ===== node tables: packed bf16 rows, 32 u32 (=64 ch) per node =====
__device__ __forceinline__ void fma8_32(const float* xv, const float* __restrict__ W,
                                        int k0, int coloff, float* acc) {
#pragma unroll
    for (int t = 0; t < 8; t++) {
        const float* wr = W + (k0 + t) * 64 + coloff;
#pragma unroll
        for (int j = 0; j < 32; j++) acc[j] = fmaf(xv[t], wr[j], acc[j]);
    }
}

// ---- layer-1 GEMM (wave-split): x [N,128] @ Wf[128,64] -> hs bf16; scale=dinv ----
__global__ void __launch_bounds__(256) k_gemm_in_ws(const void* __restrict__ x,
                                                    const float* __restrict__ Wf,
                                                    const float* __restrict__ dinv,
                                                    unsigned int* __restrict__ hs,
                                                    const int* __restrict__ flag) {
    int wv = __builtin_amdgcn_readfirstlane(threadIdx.x >> 6);  // 0..3, scalar
    int wid = blockIdx.x * 4 + wv;
    int group = wid >> 1;
    int half = wid & 1;          // scalar: col-half
    int lane = threadIdx.x & 63;
    int node = group * 64 + lane;
    if (node >= N_NODES) return;
    int bf = flag[1];
    int coloff = half * 32;
    float acc[32];
#pragma unroll
    for (int j = 0; j < 32; j++) acc[j] = 0.f;
    if (bf) {
        const unsigned short* xp = (const unsigned short*)x + (size_t)node * F_IN;
#pragma unroll 2
        for (int k0 = 0; k0 < F_IN; k0 += 8) {
            short8 raw = *(const short8*)(xp + k0);
            float xv[8];
#pragma unroll
            for (int t = 0; t < 8; t++) xv[t] = bfbits2f((unsigned short)raw[t]);
            fma8_32(xv, Wf, k0, coloff, acc);
        }
    } else {
        const float* xp = (const float*)x + (size_t)node * F_IN;
#pragma unroll 2
        for (int k0 = 0; k0 < F_IN; k0 += 8) {
            float4 a = *(const float4*)(xp + k0);
            float4 b = *(const float4*)(xp + k0 + 4);
            float xv[8] = {a.x, a.y, a.z, a.w, b.x, b.y, b.z, b.w};
            fma8_32(xv, Wf, k0, coloff, acc);
        }
    }
    float s = dinv[node];
    unsigned int* op = hs + (size_t)node * 32 + half * 16;
#pragma unroll
    for (int j = 0; j < 32; j += 2) op[j >> 1] = pack2bf(acc[j] * s, acc[j + 1] * s);
}

// ---- layer-2 GEMM (wave-split): in bf16 [N,64] @ W[64][64] -> out bf16; scale=dinv ----
__global__ void __launch_bounds__(256) k_gemm64_ws(const unsigned int* __restrict__ in,
                                                   const float* __restrict__ W,
                                                   const float* __restrict__ dinv,
                                                   unsigned int* __restrict__ out) {
    int wv = __builtin_amdgcn_readfirstlane(threadIdx.x >> 6);
    int wid = blockIdx.x * 4 + wv;
    int group = wid >> 1;
    int half = wid & 1;
    int lane = threadIdx.x & 63;
    int node = group * 64 + lane;
    if (node >= N_NODES) return;
    int coloff = half * 32;
    float acc[32];
#pragma unroll
    for (int j = 0; j < 32; j++) acc[j] = 0.f;
    const unsigned short* hp = (const unsigned short*)(in + (size_t)node * 32);
#pragma unroll 2
    for (int k0 = 0; k0 < 64; k0 += 8) {
        short8 raw = *(const short8*)(hp + k0);
        float xv[8];
#pragma unroll
        for (int t = 0; t < 8; t++) xv[t] = bfbits2f((unsigned short)raw[t]);
        fma8_32(xv, W, k0, coloff, acc);
    }
    float s = dinv[node];
    unsigned int* op = out + (size_t)node * 32 + half * 16;
#pragma unroll
    for (int j = 0; j < 32; j += 2) op[j >> 1] = pack2bf(acc[j] * s, acc[j + 1] * s);
}

// ---- edge-MLP projections (wave-split, 4 tasks): block = 64 nodes x 4 waves ----
__global__ void __launch_bounds__(256) k_pair_ws(unsigned int* __restrict__ h,
                                                 const float* __restrict__ W,  // L1W [128][64]
                                                 unsigned int* __restrict__ P1) {
    int task = __builtin_amdgcn_readfirstlane(threadIdx.x >> 6);  // 0..3, scalar
    int lane = threadIdx.x & 63;
    int node = blockIdx.x * 64 + lane;
    bool valid = node < N_NODES;
    int coloff = (task & 1) * 32;
    const float* Wb = W + (task >> 1) * 64 * 64;  // k-row base: P1 rows 0.., P2 rows 64..
    float acc[32];
#pragma unroll
    for (int j = 0; j < 32; j++) acc[j] = 0.f;
    if (valid) {
        const unsigned short* hp = (const unsigned short*)(h + (size_t)node * 32);
#pragma unroll 2
        for (int k0 = 0; k0 < 64; k0 += 8) {
            short8 raw = *(const short8*)(hp + k0);
            float xv[8];
#pragma unroll
            for (int t = 0; t < 8; t++) xv[t] = bfbits2f((unsigned short)raw[t]);
            fma8_32(xv, Wb, k0, coloff, acc);
        }
    }
    __syncthreads();  // all reads of this block's 64 h-rows complete before P2 writes
    if (valid) {
        unsigned int* op = (task < 2 ? P1 : h) + (size_t)node * 32 + coloff / 2;
#pragma unroll
        for (int j = 0; j < 32; j += 2) op[j >> 1] = pack2bf(acc[j], acc[j + 1]);
    }
}

// ---- fused aggregate: wave = 2 nodes; 32 lanes/node; x8 unroll for gather ILP
// (16 random lines in flight per wave on the dependent csr_src[k]->hs[src] chain) ----
__global__ void __launch_bounds__(256) k_agg(const unsigned int* __restrict__ hs,
                                             const int* __restrict__ rowptr,
                                             const int* __restrict__ csr_src,
                                             const float* __restrict__ dinv,
                                             const float* __restrict__ bias,
                                             unsigned int* __restrict__ h) {
    int waves_per_blk = blockDim.x >> 6;
    int wid = blockIdx.x * waves_per_blk + (threadIdx.x >> 6);
    int lane = threadIdx.x & 63;
    int half = lane >> 5;
    int w = lane & 31;
    int node = wid * 2 + half;
    if (node >= N_NODES) return;
    unsigned int sw = hs[(size_t)node * 32 + w];
    float a0 = lo_bf(sw), a1 = hi_bf(sw);
    int k = rowptr[node], k1 = rowptr[node + 1];
    for (; k + 7 < k1; k += 8) {
        int s0 = csr_src[k],     s1 = csr_src[k + 1], s2 = csr_src[k + 2], s3 = csr_src[k + 3];
        int s4 = csr_src[k + 4], s5 = csr_src[k + 5], s6 = csr_src[k + 6], s7 = csr_src[k + 7];
        unsigned int w0 = hs[(size_t)s0 * 32 + w];
        unsigned int w1 = hs[(size_t)s1 * 32 + w];
        unsigned int w2 = hs[(size_t)s2 * 32 + w];
        unsigned int w3 = hs[(size_t)s3 * 32 + w];
        unsigned int w4 = hs[(size_t)s4 * 32 + w];
        unsigned int w5 = hs[(size_t)s5 * 32 + w];
        unsigned int w6 = hs[(size_t)s6 * 32 + w];
        unsigned int w7 = hs[(size_t)s7 * 32 + w];
        a0 += ((lo_bf(w0) + lo_bf(w1)) + (lo_bf(w2) + lo_bf(w3)))
            + ((lo_bf(w4) + lo_bf(w5)) + (lo_bf(w6) + lo_bf(w7)));
        a1 += ((hi_bf(w0) + hi_bf(w1)) + (hi_bf(w2) + hi_bf(w3)))
            + ((hi_bf(w4) + hi_bf(w5)) + (hi_bf(w6) + hi_bf(w7)));
    }
    for (; k + 3 < k1; k += 4) {
        int s0 = csr_src[k], s1 = csr_src[k + 1], s2 = csr_src[k + 2], s3 = csr_src[k + 3];
        unsigned int w0 = hs[(size_t)s0 * 32 + w];
        unsigned int w1 = hs[(size_t)s1 * 32 + w];
        unsigned int w2 = hs[(size_t)s2 * 32 + w];
        unsigned int w3 = hs[(size_t)s3 * 32 + w];
        a0 += (lo_bf(w0) + lo_bf(w1)) + (lo_bf(w2) + lo_bf(w3));
        a1 += (hi_bf(w0) + hi_bf(w1)) + (hi_bf(w2) + hi_bf(w3));
    }
    for (; k < k1; k++) {
        unsigned int w0 = hs[(size_t)csr_src[k] * 32 + w];
        a0 += lo_bf(w0);
        a1 += hi_bf(w0);
    }
    float di = dinv[node];
    float v0 = fmaxf(fmaf(a0, di, bias[2 * w]), 0.f);
    float v1 = fmaxf(fmaf(a1, di, bias[2 * w + 1]), 0.f);
    h[(size_t)node * 32 + w] = pack2bf(v0, v1);
}

// ---- edge MLP, lane-cooperative + 4-edge ILP: 8 lanes per edge-quad.
// Each lane issues 8 independent uint4 gathers up front -> 64 random 128-B lines
// in flight per wave; weights amortize over 4 edges; lane 0 stores 4 adjacent
// outputs coalesced (32 B fp32 / 16 B bf16).
__global__ void __launch_bounds__(256) k_edge(const int* __restrict__ ei,
                       const unsigned int* __restrict__ P1, const unsigned int* __restrict__ P2,
                       const float* __restrict__ Wf, const int* __restrict__ flag,
                       void* __restrict__ out) {
    int tid = blockIdx.x * 256 + threadIdx.x;
    int g = tid >> 3;       // quad index: edges 4g .. 4g+3
    int k = tid & 7;        // sub-lane: channels j = 8k .. 8k+7
    int e0 = g * 4;
    if (e0 >= N_EDGES) return;  // N_EDGES % 4 == 0 -> e0..e0+3 all valid
    int f = flag[0];
    int r0 = load_row(ei, f, e0),     c0 = load_col(ei, f, e0);
    int r1 = load_row(ei, f, e0 + 1), c1 = load_col(ei, f, e0 + 1);
    int r2 = load_row(ei, f, e0 + 2), c2 = load_col(ei, f, e0 + 2);
    int r3 = load_row(ei, f, e0 + 3), c3 = load_col(ei, f, e0 + 3);
    // issue all 8 gathers before any compute
    uint4 ua0 = *(const uint4*)(P1 + (size_t)r0 * 32 + k * 4);
    uint4 ub0 = *(const uint4*)(P2 + (size_t)c0 * 32 + k * 4);
    uint4 ua1 = *(const uint4*)(P1 + (size_t)r1 * 32 + k * 4);
    uint4 ub1 = *(const uint4*)(P2 + (size_t)c1 * 32 + k * 4);
    uint4 ua2 = *(const uint4*)(P1 + (size_t)r2 * 32 + k * 4);
    uint4 ub2 = *(const uint4*)(P2 + (size_t)c2 * 32 + k * 4);
    uint4 ua3 = *(const uint4*)(P1 + (size_t)r3 * 32 + k * 4);
    uint4 ub3 = *(const uint4*)(P2 + (size_t)c3 * 32 + k * 4);
    float l1b[8], l2w[16];
#pragma unroll
    for (int t = 0; t < 8; t++) l1b[t] = Wf[WF_L1B + k * 8 + t];
#pragma unroll
    for (int t = 0; t < 16; t++) l2w[t] = Wf[WF_L2W + k * 16 + t];
    float s0[4] = {0.f, 0.f, 0.f, 0.f}, s1[4] = {0.f, 0.f, 0.f, 0.f};
    auto edge_mlp = [&](const uint4& ua, const uint4& ub, int i) {
        unsigned int wa[4] = {ua.x, ua.y, ua.z, ua.w};
        unsigned int wb[4] = {ub.x, ub.y, ub.z, ub.w};
#pragma unroll
        for (int t = 0; t < 4; t++) {
            float z;
            z = fmaxf(lo_bf(wa[t]) + lo_bf(wb[t]) + l1b[2 * t], 0.f);
            s0[i] = fmaf(z, l2w[4 * t + 0], s0[i]); s1[i] = fmaf(z, l2w[4 * t + 1], s1[i]);
            z = fmaxf(hi_bf(wa[t]) + hi_bf(wb[t]) + l1b[2 * t + 1], 0.f);
            s0[i] = fmaf(z, l2w[4 * t + 2], s0[i]); s1[i] = fmaf(z, l2w[4 * t + 3], s1[i]);
        }
    };
    edge_mlp(ua0, ub0, 0);
    edge_mlp(ua1, ub1, 1);
    edge_mlp(ua2, ub2, 2);
    edge_mlp(ua3, ub3, 3);
#pragma unroll
    for (int off = 1; off < 8; off <<= 1) {
#pragma unroll
        for (int i = 0; i < 4; i++) {
            s0[i] += __shfl_xor(s0[i], off);
            s1[i] += __shfl_xor(s1[i], off);
        }
    }
    if (k == 0) {
        float b0f = Wf[WF_L2B + 0], b1f = Wf[WF_L2B + 1];
        float z0[4], z1[4];
#pragma unroll
        for (int i = 0; i < 4; i++) {
            float za = s0[i] + b0f, zb = s1[i] + b1f;
            float m = fmaxf(za, zb);
            float lse = m + __logf(__expf(za - m) + __expf(zb - m));
            z0[i] = za - lse; z1[i] = zb - lse;
        }
        if (flag[1]) {
            uint4 v;
            v.x = pack2bf(z0[0], z1[0]); v.y = pack2bf(z0[1], z1[1]);
            v.z = pack2bf(z0[2], z1[2]); v.w = pack2bf(z0[3], z1[3]);
            *(uint4*)((unsigned int*)out + e0) = v;
        } else {
            float4 v01, v23;
            v01.x = z0[0]; v01.y = z1[0]; v01.z = z0[1]; v01.w = z1[1];
            v23.x = z0[2]; v23.y = z1[2]; v23.z = z0[3]; v23.w = z1[3];
            float4* op = (float4*)((float2*)out + e0);
            op[0] = v01;
            op[1] = v23;
        }
    }
}

extern "C" void kernel_launch(void* const* d_in, const int* in_sizes, int n_in,
                              void* d_out, int out_size, void* d_ws, size_t ws_size,
                              hipStream_t stream) {
    const void* x   = d_in[0];
    const int*  ei  = (const int*)d_in[1];

    char* ws = (char*)d_ws;
    constexpr size_t KB = 1024;

    int*   deg    = (int*)(ws);                    // 400 KB
    float* dinv   = (float*)(ws + 400 * KB);       // 400 KB
    int*   rowptr = (int*)(ws + 800 * KB);         // 400 KB + 4
    int*   flag   = (int*)(ws + 1204 * KB);        // 8 B
    int*   bsum   = (int*)(ws + 1208 * KB);        // 392 B
    int*   boff   = (int*)(ws + 1212 * KB);        // 392 B
    float* Wf     = (float*)(ws + 1216 * KB);      // 83.2 KB -> ends 1299.2 KB
    int*   pos    = (int*)(ws + 1300 * KB);        // 6400 KB -> ends 7700
    int*   csrsrc = (int*)(ws + 7700 * KB);        // 6400 KB -> ends 14100
    unsigned int* hs = (unsigned int*)(ws + 20500 * KB);  // 12800 KB (later P1)
    unsigned int* h  = (unsigned int*)(ws + 33300 * KB);  // 12800 KB (later P2)

    // detect + deg-zero fused
    k_detect<<<SCAN_NB, 1024, 0, stream>>>(ei, (const unsigned int*)x, flag, deg);
    k_prep<<<(WF_TOT + 255) / 256, 256, 0, stream>>>(d_in[2], d_in[4], d_in[6], d_in[3],
                                                     d_in[5], d_in[7], d_in[8], d_in[9],
                                                     flag, Wf);
    // deg count + per-edge slot rank (atomic return) -> fill needs no atomics
    k_deg<<<(N_EDGES + 255) / 256, 256, 0, stream>>>(ei, flag, deg, pos);

    // CSR build (scan1 also emits dinv)
    k_scan1<<<SCAN_NB, 1024, 0, stream>>>(deg, rowptr, bsum, dinv);
    k_scan2<<<1, 128, 0, stream>>>(bsum, boff, rowptr);
    k_scan3<<<SCAN_NB, 1024, 0, stream>>>(rowptr, boff);
    k_fill<<<(N_EDGES + 255) / 256, 256, 0, stream>>>(ei, flag, rowptr, pos, csrsrc);

    // wave-split grids: 2 waves/node-group(64) for gemms, 4 task-waves/64-node block for pair
    const int G = (N_NODES + 63) / 64;          // 1563 node groups
    const int gemm_blocks = (G * 2 + 3) / 4;    // 782

    // layer 1
    k_gemm_in_ws<<<gemm_blocks, 256, 0, stream>>>(x, Wf + WF_W1, dinv, hs, flag);
    k_agg<<<(N_NODES / 2 + 3) / 4, 256, 0, stream>>>(hs, rowptr, csrsrc, dinv, Wf + WF_B1, h);

    // layer 2
    k_gemm64_ws<<<gemm_blocks, 256, 0, stream>>>(h, Wf + WF_W2, dinv, hs);
    k_agg<<<(N_NODES / 2 + 3) / 4, 256, 0, stream>>>(hs, rowptr, csrsrc, dinv, Wf + WF_B2, h);

    // edge MLP: P1 -> hs, P2 in place on h (barrier-protected); original-order edge pass
    k_pair_ws<<<G, 256, 0, stream>>>(h, Wf + WF_L1W, hs);
    // 8 lanes per edge-quad -> 2 threads/edge -> 3.2M threads
    k_edge<<<(N_EDGES * 2 + 255) / 256, 256, 0, stream>>>(ei, hs, h, Wf, flag, d_out);
}

// Round 6
// 379.906 us; speedup vs baseline: 1.3443x; 1.0948x over previous
//
#include <hip/hip_runtime.h>
#include <hip/hip_bf16.h>

#define N_NODES 100000
#define N_EDGES 1600000
#define F_IN 128
#define HID 64
#define SCAN_NB 98   // ceil(100000/1024) — grid for detect
#define NBUCK 782    // ceil(100000/128) column buckets
#define BSH 7        // 128 nodes per bucket
#define NSCB 392     // blocks for count/scatter passes

typedef __attribute__((ext_vector_type(8))) short short8;

__device__ __forceinline__ float bfbits2f(unsigned short u) {
    union { unsigned int i; float f; } v;
    v.i = ((unsigned int)u) << 16;
    return v.f;
}
__device__ __forceinline__ unsigned short f2bfbits(float f) {
    union { float f; unsigned int i; } v;
    v.f = f;
    unsigned int r = v.i + 0x7FFFu + ((v.i >> 16) & 1u);  // RNE
    return (unsigned short)(r >> 16);
}
__device__ __forceinline__ unsigned int pack2bf(float a, float b) {
    return ((unsigned int)f2bfbits(b) << 16) | (unsigned int)f2bfbits(a);
}
__device__ __forceinline__ float lo_bf(unsigned int w) { return bfbits2f((unsigned short)(w & 0xFFFF)); }
__device__ __forceinline__ float hi_bf(unsigned int w) { return bfbits2f((unsigned short)(w >> 16)); }

// ---- detect flags AND zero bucket counters; block 0 does flag logic ----
__global__ void k_detect(const int* __restrict__ ei, const unsigned int* __restrict__ x32,
                         int* __restrict__ flag, int* __restrict__ gcount) {
    int gid = blockIdx.x * 1024 + threadIdx.x;
    if (gid < NBUCK) gcount[gid] = 0;
    if (blockIdx.x != 0) return;
    __shared__ int s_odd, s_cnt;
    if (threadIdx.x == 0) { s_odd = 0; s_cnt = 0; }
    __syncthreads();
    int t = threadIdx.x;  // 1024 threads
    if (ei[2 * t + 1] != 0) atomicOr(&s_odd, 1);
    if (t < 256) {
        unsigned int u = x32[t];
        unsigned int e = (u >> 7) & 0xFF;
        if (e >= 0x68 && e <= 0x97) atomicAdd(&s_cnt, 1);
    }
    __syncthreads();
    if (t == 0) {
        flag[0] = (s_odd == 0) ? 1 : 0;
        flag[1] = (s_cnt >= 160) ? 1 : 0;
    }
}

__device__ __forceinline__ int clampN(int v) {
    v = v < 0 ? 0 : v;
    return v > (N_NODES - 1) ? (N_NODES - 1) : v;
}
__device__ __forceinline__ int load_row(const int* __restrict__ ei, int f, int e) {
    return clampN(f ? ei[2 * e] : ei[e]);
}
__device__ __forceinline__ int load_col(const int* __restrict__ ei, int f, int e) {
    return clampN(f ? ei[2 * (N_EDGES + e)] : ei[N_EDGES + e]);
}

// ---- fp32 weight scratch layout (floats) ----
#define WF_W1   0
#define WF_W2   8192
#define WF_L1W  12288
#define WF_B1   20480
#define WF_B2   20544
#define WF_L1B  20608
#define WF_L2W  20672
#define WF_L2B  20800
#define WF_TOT  20802

__global__ void k_prep(const void* W1, const void* W2, const void* L1W,
                       const void* b1, const void* b2, const void* L1b,
                       const void* L2W, const void* L2b,
                       const int* __restrict__ flag, float* __restrict__ Wf) {
    int idx = blockIdx.x * blockDim.x + threadIdx.x;
    if (idx >= WF_TOT) return;
    int bf = flag[1];
    const void* src; int k;
    if      (idx < WF_W2)  { src = W1;  k = idx; }
    else if (idx < WF_L1W) { src = W2;  k = idx - WF_W2; }
    else if (idx < WF_B1)  { src = L1W; k = idx - WF_L1W; }
    else if (idx < WF_B2)  { src = b1;  k = idx - WF_B1; }
    else if (idx < WF_L1B) { src = b2;  k = idx - WF_B2; }
    else if (idx < WF_L2W) { src = L1b; k = idx - WF_L1B; }
    else if (idx < WF_L2B) { src = L2W; k = idx - WF_L2W; }
    else                   { src = L2b; k = idx - WF_L2B; }
    Wf[idx] = bf ? bfbits2f(((const unsigned short*)src)[k]) : ((const float*)src)[k];
}

// ===== bucketed CSR build: replaces per-node global atomics (k_deg) with
// per-block LDS histograms over 782 column-buckets (128 nodes each). =====

// ---- pass 1: global bucket counts via LDS histogram (300K global adds total) ----
__global__ void __launch_bounds__(256) k_bcount(const int* __restrict__ ei,
                                                const int* __restrict__ flag,
                                                int* __restrict__ gcount) {
    __shared__ int hist[NBUCK];
    for (int t = threadIdx.x; t < NBUCK; t += 256) hist[t] = 0;
    __syncthreads();
    int f = flag[0];
    const int EPB = (N_EDGES + NSCB - 1) / NSCB;
    int base = blockIdx.x * EPB;
    int end = base + EPB; if (end > N_EDGES) end = N_EDGES;
    for (int e = base + threadIdx.x; e < end; e += 256)
        atomicAdd(&hist[load_col(ei, f, e) >> BSH], 1);
    __syncthreads();
    for (int t = threadIdx.x; t < NBUCK; t += 256)
        if (hist[t]) atomicAdd(&gcount[t], hist[t]);
}

// ---- pass 2: exclusive scan of 782 bucket counts -> bbase, cursor ----
__global__ void k_bscan(const int* __restrict__ gcount, int* __restrict__ cursor,
                        int* __restrict__ bbase, int* __restrict__ rowptr) {
    __shared__ int s[1024];
    int t = threadIdx.x;
    int v = (t < NBUCK) ? gcount[t] : 0;
    s[t] = v; __syncthreads();
    for (int off = 1; off < 1024; off <<= 1) {
        int add = (t >= off) ? s[t - off] : 0;
        __syncthreads();
        s[t] += add;
        __syncthreads();
    }
    if (t < NBUCK) { int ex = s[t] - v; cursor[t] = ex; bbase[t] = ex; }
    if (t == 0) { bbase[NBUCK] = N_EDGES; rowptr[N_NODES] = N_EDGES; }
}

// ---- pass 3: scatter edges into bucket-contiguous tmp, packed (r<<7)|c_local.
// Per-block: rebuild LDS hist, claim per-bucket bases with ONE cursor atomic per
// (block,bucket), then rank via LDS atomics. No per-node global atomics. ----
__global__ void __launch_bounds__(256) k_bscatter(const int* __restrict__ ei,
                                                  const int* __restrict__ flag,
                                                  int* __restrict__ cursor,
                                                  unsigned int* __restrict__ tmp) {
    __shared__ int hist[NBUCK];
    __shared__ int lbase[NBUCK];
    for (int t = threadIdx.x; t < NBUCK; t += 256) hist[t] = 0;
    __syncthreads();
    int f = flag[0];
    const int EPB = (N_EDGES + NSCB - 1) / NSCB;
    int base = blockIdx.x * EPB;
    int end = base + EPB; if (end > N_EDGES) end = N_EDGES;
    for (int e = base + threadIdx.x; e < end; e += 256)
        atomicAdd(&hist[load_col(ei, f, e) >> BSH], 1);
    __syncthreads();
    for (int t = threadIdx.x; t < NBUCK; t += 256) {
        int hv = hist[t];
        lbase[t] = hv ? atomicAdd(&cursor[t], hv) : 0;
    }
    __syncthreads();
    for (int t = threadIdx.x; t < NBUCK; t += 256) hist[t] = 0;  // reuse as rank cursor
    __syncthreads();
    for (int e = base + threadIdx.x; e < end; e += 256) {
        int r = load_row(ei, f, e), c = load_col(ei, f, e);
        int b = c >> BSH;
        int rank = atomicAdd(&hist[b], 1);
        tmp[lbase[b] + rank] = ((unsigned int)r << BSH) | (unsigned int)(c & 127);
    }
}

// ---- pass 4: per-bucket sub-CSR entirely in LDS: counts, scan, ranks.
// One block per bucket (~2048 edges, 8 KB L2-hot region). Emits csr_src,
// rowptr and dinv for its 128 nodes — replaces scan1/2/3 + k_fill. ----
__global__ void __launch_bounds__(256) k_bcsr(const unsigned int* __restrict__ tmp,
                                              const int* __restrict__ bbase,
                                              int* __restrict__ rowptr,
                                              float* __restrict__ dinv,
                                              int* __restrict__ csr_src) {
    __shared__ int nh[128];    // per-node counts (stable after count phase)
    __shared__ int nrp[128];   // inclusive prefix
    __shared__ int ncur[128];  // placement cursor
    int nb = blockIdx.x;
    int s0 = bbase[nb], s1 = bbase[nb + 1];
    int cnt = s1 - s0;
    int t = threadIdx.x;
    if (t < 128) { nh[t] = 0; ncur[t] = 0; }
    __syncthreads();
    for (int i = t; i < cnt; i += 256)
        atomicAdd(&nh[tmp[s0 + i] & 127], 1);
    __syncthreads();
    if (t < 128) nrp[t] = nh[t];
    __syncthreads();
    for (int off = 1; off < 128; off <<= 1) {
        int add = (t < 128 && t >= off) ? nrp[t - off] : 0;
        __syncthreads();
        if (t < 128) nrp[t] += add;
        __syncthreads();
    }
    int nodeBase = nb * 128;
    if (t < 128 && nodeBase + t < N_NODES) {
        rowptr[nodeBase + t] = s0 + nrp[t] - nh[t];  // exclusive prefix
        dinv[nodeBase + t] = rsqrtf((float)(nh[t] + 1));
    }
    __syncthreads();
    for (int i = t; i < cnt; i += 256) {
        unsigned int v = tmp[s0 + i];
        int cl = v & 127;
        int rank = atomicAdd(&ncur[cl], 1);
        csr_src[s0 + (nrp[cl] - nh[cl]) + rank] = (int)(v >> BSH);
    }
}

// ===== node tables: packed bf16 rows, 32 u32 (=64 ch) per node =====
__device__ __forceinline__ void fma8_32(const float* xv, const float* __restrict__ W,
                                        int k0, int coloff, float* acc) {
#pragma unroll
    for (int t = 0; t < 8; t++) {
        const float* wr = W + (k0 + t) * 64 + coloff;
#pragma unroll
        for (int j = 0; j < 32; j++) acc[j] = fmaf(xv[t], wr[j], acc[j]);
    }
}

// ---- layer-1 GEMM (wave-split): x [N,128] @ Wf[128,64] -> hs bf16; scale=dinv ----
__global__ void __launch_bounds__(256) k_gemm_in_ws(const void* __restrict__ x,
                                                    const float* __restrict__ Wf,
                                                    const float* __restrict__ dinv,
                                                    unsigned int* __restrict__ hs,
                                                    const int* __restrict__ flag) {
    int wv = __builtin_amdgcn_readfirstlane(threadIdx.x >> 6);  // 0..3, scalar
    int wid = blockIdx.x * 4 + wv;
    int group = wid >> 1;
    int half = wid & 1;          // scalar: col-half
    int lane = threadIdx.x & 63;
    int node = group * 64 + lane;
    if (node >= N_NODES) return;
    int bf = flag[1];
    int coloff = half * 32;
    float acc[32];
#pragma unroll
    for (int j = 0; j < 32; j++) acc[j] = 0.f;
    if (bf) {
        const unsigned short* xp = (const unsigned short*)x + (size_t)node * F_IN;
#pragma unroll 2
        for (int k0 = 0; k0 < F_IN; k0 += 8) {
            short8 raw = *(const short8*)(xp + k0);
            float xv[8];
#pragma unroll
            for (int t = 0; t < 8; t++) xv[t] = bfbits2f((unsigned short)raw[t]);
            fma8_32(xv, Wf, k0, coloff, acc);
        }
    } else {
        const float* xp = (const float*)x + (size_t)node * F_IN;
#pragma unroll 2
        for (int k0 = 0; k0 < F_IN; k0 += 8) {
            float4 a = *(const float4*)(xp + k0);
            float4 b = *(const float4*)(xp + k0 + 4);
            float xv[8] = {a.x, a.y, a.z, a.w, b.x, b.y, b.z, b.w};
            fma8_32(xv, Wf, k0, coloff, acc);
        }
    }
    float s = dinv[node];
    unsigned int* op = hs + (size_t)node * 32 + half * 16;
#pragma unroll
    for (int j = 0; j < 32; j += 2) op[j >> 1] = pack2bf(acc[j] * s, acc[j + 1] * s);
}

// ---- layer-2 GEMM (wave-split): in bf16 [N,64] @ W[64][64] -> out bf16; scale=dinv ----
__global__ void __launch_bounds__(256) k_gemm64_ws(const unsigned int* __restrict__ in,
                                                   const float* __restrict__ W,
                                                   const float* __restrict__ dinv,
                                                   unsigned int* __restrict__ out) {
    int wv = __builtin_amdgcn_readfirstlane(threadIdx.x >> 6);
    int wid = blockIdx.x * 4 + wv;
    int group = wid >> 1;
    int half = wid & 1;
    int lane = threadIdx.x & 63;
    int node = group * 64 + lane;
    if (node >= N_NODES) return;
    int coloff = half * 32;
    float acc[32];
#pragma unroll
    for (int j = 0; j < 32; j++) acc[j] = 0.f;
    const unsigned short* hp = (const unsigned short*)(in + (size_t)node * 32);
#pragma unroll 2
    for (int k0 = 0; k0 < 64; k0 += 8) {
        short8 raw = *(const short8*)(hp + k0);
        float xv[8];
#pragma unroll
        for (int t = 0; t < 8; t++) xv[t] = bfbits2f((unsigned short)raw[t]);
        fma8_32(xv, W, k0, coloff, acc);
    }
    float s = dinv[node];
    unsigned int* op = out + (size_t)node * 32 + half * 16;
#pragma unroll
    for (int j = 0; j < 32; j += 2) op[j >> 1] = pack2bf(acc[j] * s, acc[j + 1] * s);
}

// ---- edge-MLP projections (wave-split, 4 tasks): block = 64 nodes x 4 waves ----
__global__ void __launch_bounds__(256) k_pair_ws(unsigned int* __restrict__ h,
                                                 const float* __restrict__ W,  // L1W [128][64]
                                                 unsigned int* __restrict__ P1) {
    int task = __builtin_amdgcn_readfirstlane(threadIdx.x >> 6);  // 0..3, scalar
    int lane = threadIdx.x & 63;
    int node = blockIdx.x * 64 + lane;
    bool valid = node < N_NODES;
    int coloff = (task & 1) * 32;
    const float* Wb = W + (task >> 1) * 64 * 64;  // k-row base: P1 rows 0.., P2 rows 64..
    float acc[32];
#pragma unroll
    for (int j = 0; j < 32; j++) acc[j] = 0.f;
    if (valid) {
        const unsigned short* hp = (const unsigned short*)(h + (size_t)node * 32);
#pragma unroll 2
        for (int k0 = 0; k0 < 64; k0 += 8) {
            short8 raw = *(const short8*)(hp + k0);
            float xv[8];
#pragma unroll
            for (int t = 0; t < 8; t++) xv[t] = bfbits2f((unsigned short)raw[t]);
            fma8_32(xv, Wb, k0, coloff, acc);
        }
    }
    __syncthreads();  // all reads of this block's 64 h-rows complete before P2 writes
    if (valid) {
        unsigned int* op = (task < 2 ? P1 : h) + (size_t)node * 32 + coloff / 2;
#pragma unroll
        for (int j = 0; j < 32; j += 2) op[j >> 1] = pack2bf(acc[j], acc[j + 1]);
    }
}

// ---- fused aggregate: wave = 2 nodes; 32 lanes/node; x8 unroll for gather ILP ----
__global__ void __launch_bounds__(256) k_agg(const unsigned int* __restrict__ hs,
                                             const int* __restrict__ rowptr,
                                             const int* __restrict__ csr_src,
                                             const float* __restrict__ dinv,
                                             const float* __restrict__ bias,
                                             unsigned int* __restrict__ h) {
    int waves_per_blk = blockDim.x >> 6;
    int wid = blockIdx.x * waves_per_blk + (threadIdx.x >> 6);
    int lane = threadIdx.x & 63;
    int half = lane >> 5;
    int w = lane & 31;
    int node = wid * 2 + half;
    if (node >= N_NODES) return;
    unsigned int sw = hs[(size_t)node * 32 + w];
    float a0 = lo_bf(sw), a1 = hi_bf(sw);
    int k = rowptr[node], k1 = rowptr[node + 1];
    for (; k + 7 < k1; k += 8) {
        int s0 = csr_src[k],     s1 = csr_src[k + 1], s2 = csr_src[k + 2], s3 = csr_src[k + 3];
        int s4 = csr_src[k + 4], s5 = csr_src[k + 5], s6 = csr_src[k + 6], s7 = csr_src[k + 7];
        unsigned int w0 = hs[(size_t)s0 * 32 + w];
        unsigned int w1 = hs[(size_t)s1 * 32 + w];
        unsigned int w2 = hs[(size_t)s2 * 32 + w];
        unsigned int w3 = hs[(size_t)s3 * 32 + w];
        unsigned int w4 = hs[(size_t)s4 * 32 + w];
        unsigned int w5 = hs[(size_t)s5 * 32 + w];
        unsigned int w6 = hs[(size_t)s6 * 32 + w];
        unsigned int w7 = hs[(size_t)s7 * 32 + w];
        a0 += ((lo_bf(w0) + lo_bf(w1)) + (lo_bf(w2) + lo_bf(w3)))
            + ((lo_bf(w4) + lo_bf(w5)) + (lo_bf(w6) + lo_bf(w7)));
        a1 += ((hi_bf(w0) + hi_bf(w1)) + (hi_bf(w2) + hi_bf(w3)))
            + ((hi_bf(w4) + hi_bf(w5)) + (hi_bf(w6) + hi_bf(w7)));
    }
    for (; k + 3 < k1; k += 4) {
        int s0 = csr_src[k], s1 = csr_src[k + 1], s2 = csr_src[k + 2], s3 = csr_src[k + 3];
        unsigned int w0 = hs[(size_t)s0 * 32 + w];
        unsigned int w1 = hs[(size_t)s1 * 32 + w];
        unsigned int w2 = hs[(size_t)s2 * 32 + w];
        unsigned int w3 = hs[(size_t)s3 * 32 + w];
        a0 += (lo_bf(w0) + lo_bf(w1)) + (lo_bf(w2) + lo_bf(w3));
        a1 += (hi_bf(w0) + hi_bf(w1)) + (hi_bf(w2) + hi_bf(w3));
    }
    for (; k < k1; k++) {
        unsigned int w0 = hs[(size_t)csr_src[k] * 32 + w];
        a0 += lo_bf(w0);
        a1 += hi_bf(w0);
    }
    float di = dinv[node];
    float v0 = fmaxf(fmaf(a0, di, bias[2 * w]), 0.f);
    float v1 = fmaxf(fmaf(a1, di, bias[2 * w + 1]), 0.f);
    h[(size_t)node * 32 + w] = pack2bf(v0, v1);
}

// ---- edge MLP, lane-cooperative + 4-edge ILP: 8 lanes per edge-quad ----
__global__ void __launch_bounds__(256) k_edge(const int* __restrict__ ei,
                       const unsigned int* __restrict__ P1, const unsigned int* __restrict__ P2,
                       const float* __restrict__ Wf, const int* __restrict__ flag,
                       void* __restrict__ out) {
    int tid = blockIdx.x * 256 + threadIdx.x;
    int g = tid >> 3;       // quad index: edges 4g .. 4g+3
    int k = tid & 7;        // sub-lane: channels j = 8k .. 8k+7
    int e0 = g * 4;
    if (e0 >= N_EDGES) return;  // N_EDGES % 4 == 0 -> e0..e0+3 all valid
    int f = flag[0];
    int r0 = load_row(ei, f, e0),     c0 = load_col(ei, f, e0);
    int r1 = load_row(ei, f, e0 + 1), c1 = load_col(ei, f, e0 + 1);
    int r2 = load_row(ei, f, e0 + 2), c2 = load_col(ei, f, e0 + 2);
    int r3 = load_row(ei, f, e0 + 3), c3 = load_col(ei, f, e0 + 3);
    // issue all 8 gathers before any compute
    uint4 ua0 = *(const uint4*)(P1 + (size_t)r0 * 32 + k * 4);
    uint4 ub0 = *(const uint4*)(P2 + (size_t)c0 * 32 + k * 4);
    uint4 ua1 = *(const uint4*)(P1 + (size_t)r1 * 32 + k * 4);
    uint4 ub1 = *(const uint4*)(P2 + (size_t)c1 * 32 + k * 4);
    uint4 ua2 = *(const uint4*)(P1 + (size_t)r2 * 32 + k * 4);
    uint4 ub2 = *(const uint4*)(P2 + (size_t)c2 * 32 + k * 4);
    uint4 ua3 = *(const uint4*)(P1 + (size_t)r3 * 32 + k * 4);
    uint4 ub3 = *(const uint4*)(P2 + (size_t)c3 * 32 + k * 4);
    float l1b[8], l2w[16];
#pragma unroll
    for (int t = 0; t < 8; t++) l1b[t] = Wf[WF_L1B + k * 8 + t];
#pragma unroll
    for (int t = 0; t < 16; t++) l2w[t] = Wf[WF_L2W + k * 16 + t];
    float s0[4] = {0.f, 0.f, 0.f, 0.f}, s1[4] = {0.f, 0.f, 0.f, 0.f};
    auto edge_mlp = [&](const uint4& ua, const uint4& ub, int i) {
        unsigned int wa[4] = {ua.x, ua.y, ua.z, ua.w};
        unsigned int wb[4] = {ub.x, ub.y, ub.z, ub.w};
#pragma unroll
        for (int t = 0; t < 4; t++) {
            float z;
            z = fmaxf(lo_bf(wa[t]) + lo_bf(wb[t]) + l1b[2 * t], 0.f);
            s0[i] = fmaf(z, l2w[4 * t + 0], s0[i]); s1[i] = fmaf(z, l2w[4 * t + 1], s1[i]);
            z = fmaxf(hi_bf(wa[t]) + hi_bf(wb[t]) + l1b[2 * t + 1], 0.f);
            s0[i] = fmaf(z, l2w[4 * t + 2], s0[i]); s1[i] = fmaf(z, l2w[4 * t + 3], s1[i]);
        }
    };
    edge_mlp(ua0, ub0, 0);
    edge_mlp(ua1, ub1, 1);
    edge_mlp(ua2, ub2, 2);
    edge_mlp(ua3, ub3, 3);
#pragma unroll
    for (int off = 1; off < 8; off <<= 1) {
#pragma unroll
        for (int i = 0; i < 4; i++) {
            s0[i] += __shfl_xor(s0[i], off);
            s1[i] += __shfl_xor(s1[i], off);
        }
    }
    if (k == 0) {
        float b0f = Wf[WF_L2B + 0], b1f = Wf[WF_L2B + 1];
        float z0[4], z1[4];
#pragma unroll
        for (int i = 0; i < 4; i++) {
            float za = s0[i] + b0f, zb = s1[i] + b1f;
            float m = fmaxf(za, zb);
            float lse = m + __logf(__expf(za - m) + __expf(zb - m));
            z0[i] = za - lse; z1[i] = zb - lse;
        }
        if (flag[1]) {
            uint4 v;
            v.x = pack2bf(z0[0], z1[0]); v.y = pack2bf(z0[1], z1[1]);
            v.z = pack2bf(z0[2], z1[2]); v.w = pack2bf(z0[3], z1[3]);
            *(uint4*)((unsigned int*)out + e0) = v;
        } else {
            float4 v01, v23;
            v01.x = z0[0]; v01.y = z1[0]; v01.z = z0[1]; v01.w = z1[1];
            v23.x = z0[2]; v23.y = z1[2]; v23.z = z0[3]; v23.w = z1[3];
            float4* op = (float4*)((float2*)out + e0);
            op[0] = v01;
            op[1] = v23;
        }
    }
}

extern "C" void kernel_launch(void* const* d_in, const int* in_sizes, int n_in,
                              void* d_out, int out_size, void* d_ws, size_t ws_size,
                              hipStream_t stream) {
    const void* x   = d_in[0];
    const int*  ei  = (const int*)d_in[1];

    char* ws = (char*)d_ws;
    constexpr size_t KB = 1024;

    int*   gcount = (int*)(ws);                    // 782 ints
    int*   cursor = (int*)(ws + 4 * KB);           // 782 ints
    int*   bbase  = (int*)(ws + 8 * KB);           // 783 ints
    int*   flag   = (int*)(ws + 12 * KB);          // 8 B
    float* Wf     = (float*)(ws + 16 * KB);        // 83.2 KB -> ends ~99 KB
    float* dinv   = (float*)(ws + 400 * KB);       // 400 KB
    int*   rowptr = (int*)(ws + 800 * KB);         // 400 KB + 4
    unsigned int* tmp = (unsigned int*)(ws + 1300 * KB);  // 6400 KB -> ends 7700
    int*   csrsrc = (int*)(ws + 7700 * KB);        // 6400 KB -> ends 14100
    unsigned int* hs = (unsigned int*)(ws + 20500 * KB);  // 12800 KB (later P1)
    unsigned int* h  = (unsigned int*)(ws + 33300 * KB);  // 12800 KB (later P2)

    // detect + bucket-counter zero fused
    k_detect<<<SCAN_NB, 1024, 0, stream>>>(ei, (const unsigned int*)x, flag, gcount);
    k_prep<<<(WF_TOT + 255) / 256, 256, 0, stream>>>(d_in[2], d_in[4], d_in[6], d_in[3],
                                                     d_in[5], d_in[7], d_in[8], d_in[9],
                                                     flag, Wf);

    // bucketed CSR build: count -> scan -> scatter -> per-bucket sub-CSR (+rowptr,dinv)
    k_bcount<<<NSCB, 256, 0, stream>>>(ei, flag, gcount);
    k_bscan<<<1, 1024, 0, stream>>>(gcount, cursor, bbase, rowptr);
    k_bscatter<<<NSCB, 256, 0, stream>>>(ei, flag, cursor, tmp);
    k_bcsr<<<NBUCK, 256, 0, stream>>>(tmp, bbase, rowptr, dinv, csrsrc);

    // wave-split grids: 2 waves/node-group(64) for gemms, 4 task-waves/64-node block for pair
    const int G = (N_NODES + 63) / 64;          // 1563 node groups
    const int gemm_blocks = (G * 2 + 3) / 4;    // 782

    // layer 1
    k_gemm_in_ws<<<gemm_blocks, 256, 0, stream>>>(x, Wf + WF_W1, dinv, hs, flag);
    k_agg<<<(N_NODES / 2 + 3) / 4, 256, 0, stream>>>(hs, rowptr, csrsrc, dinv, Wf + WF_B1, h);

    // layer 2
    k_gemm64_ws<<<gemm_blocks, 256, 0, stream>>>(h, Wf + WF_W2, dinv, hs);
    k_agg<<<(N_NODES / 2 + 3) / 4, 256, 0, stream>>>(hs, rowptr, csrsrc, dinv, Wf + WF_B2, h);

    // edge MLP: P1 -> hs, P2 in place on h (barrier-protected); original-order edge pass
    k_pair_ws<<<G, 256, 0, stream>>>(h, Wf + WF_L1W, hs);
    // 8 lanes per edge-quad -> 2 threads/edge -> 3.2M threads
    k_edge<<<(N_EDGES * 2 + 255) / 256, 256, 0, stream>>>(ei, hs, h, Wf, flag, d_out);
}

// Round 7
// 372.265 us; speedup vs baseline: 1.3719x; 1.0205x over previous
//
#include <hip/hip_runtime.h>
#include <hip/hip_bf16.h>

#define N_NODES 100000
#define N_EDGES 1600000
#define F_IN 128
#define HID 64
#define SCAN_NB 98   // ceil(100000/1024) — grid for detect
#define NBUCK 782    // ceil(100000/128) column buckets
#define BSH 7        // 128 nodes per bucket
#define NSCB 392     // blocks for count/scatter passes

typedef __attribute__((ext_vector_type(8))) short short8;

__device__ __forceinline__ float bfbits2f(unsigned short u) {
    union { unsigned int i; float f; } v;
    v.i = ((unsigned int)u) << 16;
    return v.f;
}
__device__ __forceinline__ unsigned short f2bfbits(float f) {
    union { float f; unsigned int i; } v;
    v.f = f;
    unsigned int r = v.i + 0x7FFFu + ((v.i >> 16) & 1u);  // RNE
    return (unsigned short)(r >> 16);
}
__device__ __forceinline__ unsigned int pack2bf(float a, float b) {
    return ((unsigned int)f2bfbits(b) << 16) | (unsigned int)f2bfbits(a);
}
__device__ __forceinline__ float lo_bf(unsigned int w) { return bfbits2f((unsigned short)(w & 0xFFFF)); }
__device__ __forceinline__ float hi_bf(unsigned int w) { return bfbits2f((unsigned short)(w >> 16)); }

// ---- detect flags AND zero bucket counters; block 0 does flag logic ----
__global__ void k_detect(const int* __restrict__ ei, const unsigned int* __restrict__ x32,
                         int* __restrict__ flag, int* __restrict__ gcount) {
    int gid = blockIdx.x * 1024 + threadIdx.x;
    if (gid < NBUCK) gcount[gid] = 0;
    if (blockIdx.x != 0) return;
    __shared__ int s_odd, s_cnt;
    if (threadIdx.x == 0) { s_odd = 0; s_cnt = 0; }
    __syncthreads();
    int t = threadIdx.x;  // 1024 threads
    if (ei[2 * t + 1] != 0) atomicOr(&s_odd, 1);
    if (t < 256) {
        unsigned int u = x32[t];
        unsigned int e = (u >> 7) & 0xFF;
        if (e >= 0x68 && e <= 0x97) atomicAdd(&s_cnt, 1);
    }
    __syncthreads();
    if (t == 0) {
        flag[0] = (s_odd == 0) ? 1 : 0;
        flag[1] = (s_cnt >= 160) ? 1 : 0;
    }
}

__device__ __forceinline__ int clampN(int v) {
    v = v < 0 ? 0 : v;
    return v > (N_NODES - 1) ? (N_NODES - 1) : v;
}
__device__ __forceinline__ int load_row(const int* __restrict__ ei, int f, int e) {
    return clampN(f ? ei[2 * e] : ei[e]);
}
__device__ __forceinline__ int load_col(const int* __restrict__ ei, int f, int e) {
    return clampN(f ? ei[2 * (N_EDGES + e)] : ei[N_EDGES + e]);
}

// ---- fp32 weight scratch layout (floats) ----
#define WF_W1   0
#define WF_W2   8192
#define WF_L1W  12288
#define WF_B1   20480
#define WF_B2   20544
#define WF_L1B  20608
#define WF_L2W  20672
#define WF_L2B  20800
#define WF_TOT  20802

__global__ void k_prep(const void* W1, const void* W2, const void* L1W,
                       const void* b1, const void* b2, const void* L1b,
                       const void* L2W, const void* L2b,
                       const int* __restrict__ flag, float* __restrict__ Wf) {
    int idx = blockIdx.x * blockDim.x + threadIdx.x;
    if (idx >= WF_TOT) return;
    int bf = flag[1];
    const void* src; int k;
    if      (idx < WF_W2)  { src = W1;  k = idx; }
    else if (idx < WF_L1W) { src = W2;  k = idx - WF_W2; }
    else if (idx < WF_B1)  { src = L1W; k = idx - WF_L1W; }
    else if (idx < WF_B2)  { src = b1;  k = idx - WF_B1; }
    else if (idx < WF_L1B) { src = b2;  k = idx - WF_B2; }
    else if (idx < WF_L2W) { src = L1b; k = idx - WF_L1B; }
    else if (idx < WF_L2B) { src = L2W; k = idx - WF_L2W; }
    else                   { src = L2b; k = idx - WF_L2B; }
    Wf[idx] = bf ? bfbits2f(((const unsigned short*)src)[k]) : ((const float*)src)[k];
}

// ===== bucketed CSR build (deterministic, no global cursor atomics) =====

// ---- pass 1: LDS histogram; emit per-block hist matrix + global bucket counts ----
__global__ void __launch_bounds__(256) k_bcount(const int* __restrict__ ei,
                                                const int* __restrict__ flag,
                                                int* __restrict__ gcount,
                                                int* __restrict__ bhist) {
    __shared__ int hist[NBUCK];
    for (int t = threadIdx.x; t < NBUCK; t += 256) hist[t] = 0;
    __syncthreads();
    int f = flag[0];
    const int EPB = (N_EDGES + NSCB - 1) / NSCB;
    int base = blockIdx.x * EPB;
    int end = base + EPB; if (end > N_EDGES) end = N_EDGES;
    for (int e = base + threadIdx.x; e < end; e += 256)
        atomicAdd(&hist[load_col(ei, f, e) >> BSH], 1);
    __syncthreads();
    for (int t = threadIdx.x; t < NBUCK; t += 256) {
        int hv = hist[t];
        bhist[(size_t)blockIdx.x * NBUCK + t] = hv;   // coalesced
        if (hv) atomicAdd(&gcount[t], hv);
    }
}

// ---- pass 2a: exclusive scan of 782 bucket totals -> bbase ----
__global__ void k_bscan(const int* __restrict__ gcount,
                        int* __restrict__ bbase, int* __restrict__ rowptr) {
    __shared__ int s[1024];
    int t = threadIdx.x;
    int v = (t < NBUCK) ? gcount[t] : 0;
    s[t] = v; __syncthreads();
    for (int off = 1; off < 1024; off <<= 1) {
        int add = (t >= off) ? s[t - off] : 0;
        __syncthreads();
        s[t] += add;
        __syncthreads();
    }
    if (t < NBUCK) bbase[t] = s[t] - v;
    if (t == 0) { bbase[NBUCK] = N_EDGES; rowptr[N_NODES] = N_EDGES; }
}

// ---- pass 2b: per-(block,bucket) exact bases: bofs[b][blk] = bbase[b] + prefix ----
__global__ void __launch_bounds__(512) k_bscan2(const int* __restrict__ bhist,
                                                const int* __restrict__ bbase,
                                                int* __restrict__ bofs) {
    __shared__ int s[512];
    int b = blockIdx.x;
    int t = threadIdx.x;
    int v = (t < NSCB) ? bhist[(size_t)t * NBUCK + b] : 0;
    s[t] = v; __syncthreads();
    for (int off = 1; off < 512; off <<= 1) {
        int add = (t >= off) ? s[t - off] : 0;
        __syncthreads();
        s[t] += add;
        __syncthreads();
    }
    if (t < NSCB) bofs[(size_t)b * NSCB + t] = bbase[b] + s[t] - v;  // coalesced
}

// ---- pass 3: single-read scatter; rank via LDS atomics only ----
__global__ void __launch_bounds__(256) k_bscatter(const int* __restrict__ ei,
                                                  const int* __restrict__ flag,
                                                  const int* __restrict__ bofs,
                                                  unsigned int* __restrict__ tmp) {
    __shared__ int lbase[NBUCK];
    __shared__ int rank[NBUCK];
    for (int t = threadIdx.x; t < NBUCK; t += 256) {
        lbase[t] = bofs[(size_t)t * NSCB + blockIdx.x];
        rank[t] = 0;
    }
    __syncthreads();
    int f = flag[0];
    const int EPB = (N_EDGES + NSCB - 1) / NSCB;
    int base = blockIdx.x * EPB;
    int end = base + EPB; if (end > N_EDGES) end = N_EDGES;
    for (int e = base + threadIdx.x; e < end; e += 256) {
        int r = load_row(ei, f, e), c = load_col(ei, f, e);
        int b = c >> BSH;
        int rk = atomicAdd(&rank[b], 1);
        tmp[lbase[b] + rk] = ((unsigned int)r << BSH) | (unsigned int)(c & 127);
    }
}

// ---- pass 4: per-bucket sub-CSR entirely in LDS (emits csr_src, rowptr, dinv) ----
__global__ void __launch_bounds__(256) k_bcsr(const unsigned int* __restrict__ tmp,
                                              const int* __restrict__ bbase,
                                              int* __restrict__ rowptr,
                                              float* __restrict__ dinv,
                                              int* __restrict__ csr_src) {
    __shared__ int nh[128];    // per-node counts (stable after count phase)
    __shared__ int nrp[128];   // inclusive prefix
    __shared__ int ncur[128];  // placement cursor
    int nb = blockIdx.x;
    int s0 = bbase[nb], s1 = bbase[nb + 1];
    int cnt = s1 - s0;
    int t = threadIdx.x;
    if (t < 128) { nh[t] = 0; ncur[t] = 0; }
    __syncthreads();
    for (int i = t; i < cnt; i += 256)
        atomicAdd(&nh[tmp[s0 + i] & 127], 1);
    __syncthreads();
    if (t < 128) nrp[t] = nh[t];
    __syncthreads();
    for (int off = 1; off < 128; off <<= 1) {
        int add = (t < 128 && t >= off) ? nrp[t - off] : 0;
        __syncthreads();
        if (t < 128) nrp[t] += add;
        __syncthreads();
    }
    int nodeBase = nb * 128;
    if (t < 128 && nodeBase + t < N_NODES) {
        rowptr[nodeBase + t] = s0 + nrp[t] - nh[t];  // exclusive prefix
        dinv[nodeBase + t] = rsqrtf((float)(nh[t] + 1));
    }
    __syncthreads();
    for (int i = t; i < cnt; i += 256) {
        unsigned int v = tmp[s0 + i];
        int cl = v & 127;
        int rk = atomicAdd(&ncur[cl], 1);
        csr_src[s0 + (nrp[cl] - nh[cl]) + rk] = (int)(v >> BSH);
    }
}

// ===== node tables: packed bf16 rows, 32 u32 (=64 ch) per node =====
__device__ __forceinline__ void fma8_32(const float* xv, const float* __restrict__ W,
                                        int k0, int coloff, float* acc) {
#pragma unroll
    for (int t = 0; t < 8; t++) {
        const float* wr = W + (k0 + t) * 64 + coloff;
#pragma unroll
        for (int j = 0; j < 32; j++) acc[j] = fmaf(xv[t], wr[j], acc[j]);
    }
}

// ---- layer-1 GEMM (wave-split): x [N,128] @ Wf[128,64] -> hs bf16; scale=dinv ----
__global__ void __launch_bounds__(256) k_gemm_in_ws(const void* __restrict__ x,
                                                    const float* __restrict__ Wf,
                                                    const float* __restrict__ dinv,
                                                    unsigned int* __restrict__ hs,
                                                    const int* __restrict__ flag) {
    int wv = __builtin_amdgcn_readfirstlane(threadIdx.x >> 6);  // 0..3, scalar
    int wid = blockIdx.x * 4 + wv;
    int group = wid >> 1;
    int half = wid & 1;          // scalar: col-half
    int lane = threadIdx.x & 63;
    int node = group * 64 + lane;
    if (node >= N_NODES) return;
    int bf = flag[1];
    int coloff = half * 32;
    float acc[32];
#pragma unroll
    for (int j = 0; j < 32; j++) acc[j] = 0.f;
    if (bf) {
        const unsigned short* xp = (const unsigned short*)x + (size_t)node * F_IN;
#pragma unroll 2
        for (int k0 = 0; k0 < F_IN; k0 += 8) {
            short8 raw = *(const short8*)(xp + k0);
            float xv[8];
#pragma unroll
            for (int t = 0; t < 8; t++) xv[t] = bfbits2f((unsigned short)raw[t]);
            fma8_32(xv, Wf, k0, coloff, acc);
        }
    } else {
        const float* xp = (const float*)x + (size_t)node * F_IN;
#pragma unroll 2
        for (int k0 = 0; k0 < F_IN; k0 += 8) {
            float4 a = *(const float4*)(xp + k0);
            float4 b = *(const float4*)(xp + k0 + 4);
            float xv[8] = {a.x, a.y, a.z, a.w, b.x, b.y, b.z, b.w};
            fma8_32(xv, Wf, k0, coloff, acc);
        }
    }
    float s = dinv[node];
    unsigned int* op = hs + (size_t)node * 32 + half * 16;
#pragma unroll
    for (int j = 0; j < 32; j += 2) op[j >> 1] = pack2bf(acc[j] * s, acc[j + 1] * s);
}

// ---- layer-2 GEMM (wave-split): in bf16 [N,64] @ W[64][64] -> out bf16; scale=dinv ----
__global__ void __launch_bounds__(256) k_gemm64_ws(const unsigned int* __restrict__ in,
                                                   const float* __restrict__ W,
                                                   const float* __restrict__ dinv,
                                                   unsigned int* __restrict__ out) {
    int wv = __builtin_amdgcn_readfirstlane(threadIdx.x >> 6);
    int wid = blockIdx.x * 4 + wv;
    int group = wid >> 1;
    int half = wid & 1;
    int lane = threadIdx.x & 63;
    int node = group * 64 + lane;
    if (node >= N_NODES) return;
    int coloff = half * 32;
    float acc[32];
#pragma unroll
    for (int j = 0; j < 32; j++) acc[j] = 0.f;
    const unsigned short* hp = (const unsigned short*)(in + (size_t)node * 32);
#pragma unroll 2
    for (int k0 = 0; k0 < 64; k0 += 8) {
        short8 raw = *(const short8*)(hp + k0);
        float xv[8];
#pragma unroll
        for (int t = 0; t < 8; t++) xv[t] = bfbits2f((unsigned short)raw[t]);
        fma8_32(xv, W, k0, coloff, acc);
    }
    float s = dinv[node];
    unsigned int* op = out + (size_t)node * 32 + half * 16;
#pragma unroll
    for (int j = 0; j < 32; j += 2) op[j >> 1] = pack2bf(acc[j] * s, acc[j + 1] * s);
}

// ---- edge-MLP projections (wave-split, 4 tasks): block = 64 nodes x 4 waves ----
__global__ void __launch_bounds__(256) k_pair_ws(unsigned int* __restrict__ h,
                                                 const float* __restrict__ W,  // L1W [128][64]
                                                 unsigned int* __restrict__ P1) {
    int task = __builtin_amdgcn_readfirstlane(threadIdx.x >> 6);  // 0..3, scalar
    int lane = threadIdx.x & 63;
    int node = blockIdx.x * 64 + lane;
    bool valid = node < N_NODES;
    int coloff = (task & 1) * 32;
    const float* Wb = W + (task >> 1) * 64 * 64;  // k-row base: P1 rows 0.., P2 rows 64..
    float acc[32];
#pragma unroll
    for (int j = 0; j < 32; j++) acc[j] = 0.f;
    if (valid) {
        const unsigned short* hp = (const unsigned short*)(h + (size_t)node * 32);
#pragma unroll 2
        for (int k0 = 0; k0 < 64; k0 += 8) {
            short8 raw = *(const short8*)(hp + k0);
            float xv[8];
#pragma unroll
            for (int t = 0; t < 8; t++) xv[t] = bfbits2f((unsigned short)raw[t]);
            fma8_32(xv, Wb, k0, coloff, acc);
        }
    }
    __syncthreads();  // all reads of this block's 64 h-rows complete before P2 writes
    if (valid) {
        unsigned int* op = (task < 2 ? P1 : h) + (size_t)node * 32 + coloff / 2;
#pragma unroll
        for (int j = 0; j < 32; j += 2) op[j >> 1] = pack2bf(acc[j], acc[j + 1]);
    }
}

// ---- fused aggregate: wave = 2 nodes; 32 lanes/node; x8 unroll for gather ILP ----
__global__ void __launch_bounds__(256) k_agg(const unsigned int* __restrict__ hs,
                                             const int* __restrict__ rowptr,
                                             const int* __restrict__ csr_src,
                                             const float* __restrict__ dinv,
                                             const float* __restrict__ bias,
                                             unsigned int* __restrict__ h) {
    int waves_per_blk = blockDim.x >> 6;
    int wid = blockIdx.x * waves_per_blk + (threadIdx.x >> 6);
    int lane = threadIdx.x & 63;
    int half = lane >> 5;
    int w = lane & 31;
    int node = wid * 2 + half;
    if (node >= N_NODES) return;
    unsigned int sw = hs[(size_t)node * 32 + w];
    float a0 = lo_bf(sw), a1 = hi_bf(sw);
    int k = rowptr[node], k1 = rowptr[node + 1];
    for (; k + 7 < k1; k += 8) {
        int s0 = csr_src[k],     s1 = csr_src[k + 1], s2 = csr_src[k + 2], s3 = csr_src[k + 3];
        int s4 = csr_src[k + 4], s5 = csr_src[k + 5], s6 = csr_src[k + 6], s7 = csr_src[k + 7];
        unsigned int w0 = hs[(size_t)s0 * 32 + w];
        unsigned int w1 = hs[(size_t)s1 * 32 + w];
        unsigned int w2 = hs[(size_t)s2 * 32 + w];
        unsigned int w3 = hs[(size_t)s3 * 32 + w];
        unsigned int w4 = hs[(size_t)s4 * 32 + w];
        unsigned int w5 = hs[(size_t)s5 * 32 + w];
        unsigned int w6 = hs[(size_t)s6 * 32 + w];
        unsigned int w7 = hs[(size_t)s7 * 32 + w];
        a0 += ((lo_bf(w0) + lo_bf(w1)) + (lo_bf(w2) + lo_bf(w3)))
            + ((lo_bf(w4) + lo_bf(w5)) + (lo_bf(w6) + lo_bf(w7)));
        a1 += ((hi_bf(w0) + hi_bf(w1)) + (hi_bf(w2) + hi_bf(w3)))
            + ((hi_bf(w4) + hi_bf(w5)) + (hi_bf(w6) + hi_bf(w7)));
    }
    for (; k + 3 < k1; k += 4) {
        int s0 = csr_src[k], s1 = csr_src[k + 1], s2 = csr_src[k + 2], s3 = csr_src[k + 3];
        unsigned int w0 = hs[(size_t)s0 * 32 + w];
        unsigned int w1 = hs[(size_t)s1 * 32 + w];
        unsigned int w2 = hs[(size_t)s2 * 32 + w];
        unsigned int w3 = hs[(size_t)s3 * 32 + w];
        a0 += (lo_bf(w0) + lo_bf(w1)) + (lo_bf(w2) + lo_bf(w3));
        a1 += (hi_bf(w0) + hi_bf(w1)) + (hi_bf(w2) + hi_bf(w3));
    }
    for (; k < k1; k++) {
        unsigned int w0 = hs[(size_t)csr_src[k] * 32 + w];
        a0 += lo_bf(w0);
        a1 += hi_bf(w0);
    }
    float di = dinv[node];
    float v0 = fmaxf(fmaf(a0, di, bias[2 * w]), 0.f);
    float v1 = fmaxf(fmaf(a1, di, bias[2 * w + 1]), 0.f);
    h[(size_t)node * 32 + w] = pack2bf(v0, v1);
}

// ---- edge MLP: 8 lanes per edge-quad; DISTRIBUTED index loads (1 per lane + 8 shfl
// instead of 8 redundant loads per lane) then 8 independent uint4 gathers ----
__global__ void __launch_bounds__(256) k_edge(const int* __restrict__ ei,
                       const unsigned int* __restrict__ P1, const unsigned int* __restrict__ P2,
                       const float* __restrict__ Wf, const int* __restrict__ flag,
                       void* __restrict__ out) {
    int tid = blockIdx.x * 256 + threadIdx.x;
    int g = tid >> 3;       // quad index: edges 4g .. 4g+3
    int k = tid & 7;        // sub-lane: channels j = 8k .. 8k+7
    int e0 = g * 4;
    if (e0 >= N_EDGES) return;  // uniform per 8-lane group; N_EDGES % 4 == 0
    int lane = threadIdx.x & 63;
    int grp = lane & 56;    // base lane of this 8-group
    int f = flag[0];
    // lanes 0-3 of the group load rows, lanes 4-7 load cols
    int eL = e0 + (k & 3);
    int idx = (k < 4) ? load_row(ei, f, eL) : load_col(ei, f, eL);
    int r0 = __shfl(idx, grp + 0, 64), r1 = __shfl(idx, grp + 1, 64);
    int r2 = __shfl(idx, grp + 2, 64), r3 = __shfl(idx, grp + 3, 64);
    int c0 = __shfl(idx, grp + 4, 64), c1 = __shfl(idx, grp + 5, 64);
    int c2 = __shfl(idx, grp + 6, 64), c3 = __shfl(idx, grp + 7, 64);
    // issue all 8 gathers before any compute
    uint4 ua0 = *(const uint4*)(P1 + (size_t)r0 * 32 + k * 4);
    uint4 ub0 = *(const uint4*)(P2 + (size_t)c0 * 32 + k * 4);
    uint4 ua1 = *(const uint4*)(P1 + (size_t)r1 * 32 + k * 4);
    uint4 ub1 = *(const uint4*)(P2 + (size_t)c1 * 32 + k * 4);
    uint4 ua2 = *(const uint4*)(P1 + (size_t)r2 * 32 + k * 4);
    uint4 ub2 = *(const uint4*)(P2 + (size_t)c2 * 32 + k * 4);
    uint4 ua3 = *(const uint4*)(P1 + (size_t)r3 * 32 + k * 4);
    uint4 ub3 = *(const uint4*)(P2 + (size_t)c3 * 32 + k * 4);
    float l1b[8], l2w[16];
#pragma unroll
    for (int t = 0; t < 8; t++) l1b[t] = Wf[WF_L1B + k * 8 + t];
#pragma unroll
    for (int t = 0; t < 16; t++) l2w[t] = Wf[WF_L2W + k * 16 + t];
    float s0[4] = {0.f, 0.f, 0.f, 0.f}, s1[4] = {0.f, 0.f, 0.f, 0.f};
    auto edge_mlp = [&](const uint4& ua, const uint4& ub, int i) {
        unsigned int wa[4] = {ua.x, ua.y, ua.z, ua.w};
        unsigned int wb[4] = {ub.x, ub.y, ub.z, ub.w};
#pragma unroll
        for (int t = 0; t < 4; t++) {
            float z;
            z = fmaxf(lo_bf(wa[t]) + lo_bf(wb[t]) + l1b[2 * t], 0.f);
            s0[i] = fmaf(z, l2w[4 * t + 0], s0[i]); s1[i] = fmaf(z, l2w[4 * t + 1], s1[i]);
            z = fmaxf(hi_bf(wa[t]) + hi_bf(wb[t]) + l1b[2 * t + 1], 0.f);
            s0[i] = fmaf(z, l2w[4 * t + 2], s0[i]); s1[i] = fmaf(z, l2w[4 * t + 3], s1[i]);
        }
    };
    edge_mlp(ua0, ub0, 0);
    edge_mlp(ua1, ub1, 1);
    edge_mlp(ua2, ub2, 2);
    edge_mlp(ua3, ub3, 3);
#pragma unroll
    for (int off = 1; off < 8; off <<= 1) {
#pragma unroll
        for (int i = 0; i < 4; i++) {
            s0[i] += __shfl_xor(s0[i], off);
            s1[i] += __shfl_xor(s1[i], off);
        }
    }
    if (k == 0) {
        float b0f = Wf[WF_L2B + 0], b1f = Wf[WF_L2B + 1];
        float z0[4], z1[4];
#pragma unroll
        for (int i = 0; i < 4; i++) {
            float za = s0[i] + b0f, zb = s1[i] + b1f;
            float m = fmaxf(za, zb);
            float lse = m + __logf(__expf(za - m) + __expf(zb - m));
            z0[i] = za - lse; z1[i] = zb - lse;
        }
        if (flag[1]) {
            uint4 v;
            v.x = pack2bf(z0[0], z1[0]); v.y = pack2bf(z0[1], z1[1]);
            v.z = pack2bf(z0[2], z1[2]); v.w = pack2bf(z0[3], z1[3]);
            *(uint4*)((unsigned int*)out + e0) = v;
        } else {
            float4 v01, v23;
            v01.x = z0[0]; v01.y = z1[0]; v01.z = z0[1]; v01.w = z1[1];
            v23.x = z0[2]; v23.y = z1[2]; v23.z = z0[3]; v23.w = z1[3];
            float4* op = (float4*)((float2*)out + e0);
            op[0] = v01;
            op[1] = v23;
        }
    }
}

extern "C" void kernel_launch(void* const* d_in, const int* in_sizes, int n_in,
                              void* d_out, int out_size, void* d_ws, size_t ws_size,
                              hipStream_t stream) {
    const void* x   = d_in[0];
    const int*  ei  = (const int*)d_in[1];

    char* ws = (char*)d_ws;
    constexpr size_t KB = 1024;

    int*   gcount = (int*)(ws);                    // 782 ints
    int*   bbase  = (int*)(ws + 8 * KB);           // 783 ints
    int*   flag   = (int*)(ws + 12 * KB);          // 8 B
    float* Wf     = (float*)(ws + 16 * KB);        // 83.2 KB -> ends ~99 KB
    float* dinv   = (float*)(ws + 400 * KB);       // 400 KB
    int*   rowptr = (int*)(ws + 800 * KB);         // 400 KB + 4
    unsigned int* tmp = (unsigned int*)(ws + 1300 * KB);  // 6400 KB -> ends 7700
    int*   csrsrc = (int*)(ws + 7700 * KB);        // 6400 KB -> ends 14100
    int*   bhist  = (int*)(ws + 14100 * KB);       // 392*782*4 = 1.2 MB -> ends ~15300
    int*   bofs   = (int*)(ws + 15400 * KB);       // 1.2 MB -> ends ~16600
    unsigned int* hs = (unsigned int*)(ws + 20500 * KB);  // 12800 KB (later P1)
    unsigned int* h  = (unsigned int*)(ws + 33300 * KB);  // 12800 KB (later P2)

    // detect + bucket-counter zero fused
    k_detect<<<SCAN_NB, 1024, 0, stream>>>(ei, (const unsigned int*)x, flag, gcount);
    k_prep<<<(WF_TOT + 255) / 256, 256, 0, stream>>>(d_in[2], d_in[4], d_in[6], d_in[3],
                                                     d_in[5], d_in[7], d_in[8], d_in[9],
                                                     flag, Wf);

    // bucketed CSR build: count -> bucket scan -> per-(block,bucket) scan -> scatter -> sub-CSR
    k_bcount<<<NSCB, 256, 0, stream>>>(ei, flag, gcount, bhist);
    k_bscan<<<1, 1024, 0, stream>>>(gcount, bbase, rowptr);
    k_bscan2<<<NBUCK, 512, 0, stream>>>(bhist, bbase, bofs);
    k_bscatter<<<NSCB, 256, 0, stream>>>(ei, flag, bofs, tmp);
    k_bcsr<<<NBUCK, 256, 0, stream>>>(tmp, bbase, rowptr, dinv, csrsrc);

    // wave-split grids: 2 waves/node-group(64) for gemms, 4 task-waves/64-node block for pair
    const int G = (N_NODES + 63) / 64;          // 1563 node groups
    const int gemm_blocks = (G * 2 + 3) / 4;    // 782

    // layer 1
    k_gemm_in_ws<<<gemm_blocks, 256, 0, stream>>>(x, Wf + WF_W1, dinv, hs, flag);
    k_agg<<<(N_NODES / 2 + 3) / 4, 256, 0, stream>>>(hs, rowptr, csrsrc, dinv, Wf + WF_B1, h);

    // layer 2
    k_gemm64_ws<<<gemm_blocks, 256, 0, stream>>>(h, Wf + WF_W2, dinv, hs);
    k_agg<<<(N_NODES / 2 + 3) / 4, 256, 0, stream>>>(hs, rowptr, csrsrc, dinv, Wf + WF_B2, h);

    // edge MLP: P1 -> hs, P2 in place on h (barrier-protected); original-order edge pass
    k_pair_ws<<<G, 256, 0, stream>>>(h, Wf + WF_L1W, hs);
    // 8 lanes per edge-quad -> 2 threads/edge -> 3.2M threads
    k_edge<<<(N_EDGES * 2 + 255) / 256, 256, 0, stream>>>(ei, hs, h, Wf, flag, d_out);
}